// Round 15
// baseline (1745.893 us; speedup 1.0000x reference)
//
#include <hip/hip_runtime.h>
#include <cstdint>
#include <cstddef>

typedef unsigned short u16;
typedef __attribute__((ext_vector_type(8))) short bf16x8;
typedef __attribute__((ext_vector_type(4))) float f32x4;

#define N_TOK 16384
#define DIM   1024
#define HID   4096
#define NEXP  8
#define HR    2048
#define TAU   0.02f
#define MAXMT 264   // sum_e ceil(cnt[e]/128) bound (fix/fallback paths)
#define MAXMT2 136  // sum_e ceil(cnt[e]/256) bound (= 8 * 17)

__device__ __forceinline__ u16 f2bf(float f) {
  union { float f; uint32_t u; } x; x.f = f;
  uint32_t r = x.u + 0x7FFFu + ((x.u >> 16) & 1u);
  return (u16)(r >> 16);
}
__device__ __forceinline__ float bf2f(u16 u) {
  union { uint32_t u; float f; } x; x.u = ((uint32_t)u) << 16; return x.f;
}

__device__ __forceinline__ void async16(const void* g, const void* l) {
  auto gp = reinterpret_cast<const __attribute__((address_space(1))) uint32_t*>(
      reinterpret_cast<uintptr_t>(g));
  auto lp = reinterpret_cast<__attribute__((address_space(3))) uint32_t*>(
      reinterpret_cast<uintptr_t>(l));
  __builtin_amdgcn_global_load_lds(gp, lp, 16, 0, 0);
}

// bijective XCD-chunk remap (m204)
__device__ __forceinline__ unsigned xcd_swz(unsigned flat, unsigned nwg) {
  const unsigned xcd = flat & 7u, lid = flat >> 3;
  const unsigned q = nwg >> 3, r = nwg & 7u;
  return (xcd < r ? xcd * (q + 1u) : r * (q + 1u) + (xcd - r) * q) + lid;
}

// ---------------- transpose + fp32->bf16 convert, vectorized ----------------
template<bool SPLIT>
__global__ __launch_bounds__(256)
void transpose_cvt(const float* __restrict__ src, u16* __restrict__ hi,
                   u16* __restrict__ lo, int R, int C)
{
  __shared__ float tile[64][65];
  const size_t bofs = (size_t)blockIdx.z * R * C;
  src += bofs; hi += bofs; if (SPLIT) lo += bofs;
  const int t = threadIdx.x;
  const int c0 = blockIdx.x * 64, r0 = blockIdx.y * 64;
#pragma unroll
  for (int i = 0; i < 4; ++i) {
    const int idx = i * 256 + t;
    const int rr = idx >> 4;
    const int cc = (idx & 15) << 2;
    const float4 v = *(const float4*)(src + (size_t)(r0 + rr) * C + c0 + cc);
    tile[rr][cc] = v.x; tile[rr][cc + 1] = v.y;
    tile[rr][cc + 2] = v.z; tile[rr][cc + 3] = v.w;
  }
  __syncthreads();
#pragma unroll
  for (int i = 0; i < 4; ++i) {
    const int idx = i * 256 + t;
    const int oc = idx >> 4;
    const int rc = (idx & 15) << 2;
    float v0 = tile[rc][oc], v1 = tile[rc + 1][oc];
    float v2 = tile[rc + 2][oc], v3 = tile[rc + 3][oc];
    ushort4 h;
    h.x = f2bf(v0); h.y = f2bf(v1); h.z = f2bf(v2); h.w = f2bf(v3);
    const size_t o = (size_t)(c0 + oc) * R + r0 + rc;
    *(ushort4*)(hi + o) = h;
    if (SPLIT) {
      ushort4 l;
      l.x = f2bf(v0 - bf2f(h.x)); l.y = f2bf(v1 - bf2f(h.y));
      l.z = f2bf(v2 - bf2f(h.z)); l.w = f2bf(v3 - bf2f(h.w));
      *(ushort4*)(lo + o) = l;
    }
  }
}

// ---------------- LayerNorm -> xn_hi/xn_lo bf16, out = x (residual init) ----
__global__ __launch_bounds__(256)
void ln_kernel(const float* __restrict__ x, const float* __restrict__ g,
               const float* __restrict__ b, u16* __restrict__ xh,
               u16* __restrict__ xl, float* __restrict__ out)
{
  const int row = blockIdx.x;
  const int t = threadIdx.x;
  const float4 xv = ((const float4*)(x + (size_t)row * DIM))[t];
  float s = xv.x + xv.y + xv.z + xv.w;
  float q = xv.x * xv.x + xv.y * xv.y + xv.z * xv.z + xv.w * xv.w;
#pragma unroll
  for (int off = 32; off; off >>= 1) {
    s += __shfl_down(s, off, 64);
    q += __shfl_down(q, off, 64);
  }
  __shared__ float sm[8];
  __shared__ float mu_s, rs_s;
  const int lane = t & 63, wv = t >> 6;
  if (lane == 0) { sm[wv] = s; sm[wv + 4] = q; }
  __syncthreads();
  if (t == 0) {
    float S = sm[0] + sm[1] + sm[2] + sm[3];
    float Q = sm[4] + sm[5] + sm[6] + sm[7];
    float mu = S * (1.f / DIM);
    float var = Q * (1.f / DIM) - mu * mu;
    mu_s = mu; rs_s = rsqrtf(var + 1e-5f);
  }
  __syncthreads();
  const float mu = mu_s, rs = rs_s;
  const float4 gv = ((const float4*)g)[t];
  const float4 bv = ((const float4*)b)[t];
  float n0 = (xv.x - mu) * rs * gv.x + bv.x;
  float n1 = (xv.y - mu) * rs * gv.y + bv.y;
  float n2 = (xv.z - mu) * rs * gv.z + bv.z;
  float n3 = (xv.w - mu) * rs * gv.w + bv.w;
  ushort4 h, l;
  h.x = f2bf(n0); l.x = f2bf(n0 - bf2f(h.x));
  h.y = f2bf(n1); l.y = f2bf(n1 - bf2f(h.y));
  h.z = f2bf(n2); l.z = f2bf(n2 - bf2f(h.z));
  h.w = f2bf(n3); l.w = f2bf(n3 - bf2f(h.w));
  ((ushort4*)(xh + (size_t)row * DIM))[t] = h;
  ((ushort4*)(xl + (size_t)row * DIM))[t] = l;
  ((float4*)(out + (size_t)row * DIM))[t] = xv;
}

__device__ __forceinline__ void load_logits(const float* logits, const float* b2,
                                            int row, float l[8]) {
  const float4* lp = (const float4*)(logits + (size_t)row * 8);
  float4 a = lp[0], b = lp[1];
  l[0] = a.x + b2[0]; l[1] = a.y + b2[1]; l[2] = a.z + b2[2]; l[3] = a.w + b2[3];
  l[4] = b.x + b2[4]; l[5] = b.y + b2[5]; l[6] = b.z + b2[6]; l[7] = b.w + b2[7];
}
__device__ __forceinline__ void top2(const float l[8], int& i0, float& l0,
                                     int& i1, float& l1) {
  i0 = 0; l0 = l[0];
#pragma unroll
  for (int e = 1; e < 8; ++e) if (l[e] > l0) { l0 = l[e]; i0 = e; }
  i1 = -1; l1 = -1e30f;
#pragma unroll
  for (int e = 0; e < 8; ++e) if (e != i0 && l[e] > l1) { l1 = l[e]; i1 = e; }
}

// ---------------- pass1: flag ambiguous rows, zero their logits -------------
__global__ __launch_bounds__(256)
void pass_flag(float* __restrict__ logits, const float* __restrict__ b2,
               int* __restrict__ fixL, int* __restrict__ cntFix)
{
  __shared__ int lcnt;
  __shared__ int base;
  const int t = threadIdx.x;
  const int row = blockIdx.x * 256 + t;
  if (t == 0) lcnt = 0;
  float l[8]; load_logits(logits, b2, row, l);
  int i0, i1; float l0, l1;
  top2(l, i0, l0, i1, l1);
  float l2 = -1e30f;
#pragma unroll
  for (int e = 0; e < 8; ++e)
    if (e != i0 && e != i1 && l[e] > l2) l2 = l[e];
  const bool flag = (l1 - l2) < TAU;
  __syncthreads();
  int r = 0;
  if (flag) r = atomicAdd(&lcnt, 1);
  __syncthreads();
  if (t == 0) base = atomicAdd(cntFix, lcnt);
  __syncthreads();
  if (flag) {
    fixL[base + r] = row;
    float4 z = {0.f, 0.f, 0.f, 0.f};
    ((float4*)(logits + (size_t)row * 8))[0] = z;
    ((float4*)(logits + (size_t)row * 8))[1] = z;
  }
}

// ---------------- pass_count / scan / pass_scatter --------------------------
__global__ __launch_bounds__(256)
void pass_count(const float* __restrict__ logits, const float* __restrict__ b2,
                int* __restrict__ cnts)
{
  __shared__ int lcnt[NEXP];
  const int t = threadIdx.x;
  const int row = blockIdx.x * 256 + t;
  if (t < NEXP) lcnt[t] = 0;
  float l[8]; load_logits(logits, b2, row, l);
  int i0, i1; float l0, l1;
  top2(l, i0, l0, i1, l1);
  __syncthreads();
  atomicAdd(&lcnt[i0], 1);
  atomicAdd(&lcnt[i1], 1);
  __syncthreads();
  if (t < NEXP) atomicAdd(&cnts[t], lcnt[t]);
}

__global__ void scan_kernel(const int* __restrict__ cnts, int* __restrict__ offs,
                            int* __restrict__ tileOffs, int* __restrict__ tileOffs2)
{
  if (threadIdx.x == 0) {
    int s = 0, ts = 0, ts2 = 0;
#pragma unroll
    for (int e = 0; e < NEXP; ++e) {
      offs[e] = s; s += cnts[e];
      tileOffs[e] = ts; ts += (cnts[e] + 127) >> 7;
      tileOffs2[e] = ts2; ts2 += (cnts[e] + 255) >> 8;
    }
    offs[NEXP] = s;
    tileOffs[NEXP] = ts;
    tileOffs2[NEXP] = ts2;
  }
}

__global__ __launch_bounds__(256)
void pass_scatter(const float* __restrict__ logits, const float* __restrict__ b2,
                  const int* __restrict__ offs, int* __restrict__ cnts2,
                  int* __restrict__ rowsC, float* __restrict__ gateC)
{
  __shared__ int lcnt[NEXP];
  __shared__ int sbase[NEXP];
  const int t = threadIdx.x;
  const int row = blockIdx.x * 256 + t;
  if (t < NEXP) lcnt[t] = 0;
  float l[8]; load_logits(logits, b2, row, l);
  int i0, i1; float l0, l1;
  top2(l, i0, l0, i1, l1);
  float tt = expf(l1 - l0);            // <= 1
  float g0 = 1.f / (1.f + tt);
  float g1 = tt / (1.f + tt);
  __syncthreads();
  int r0 = atomicAdd(&lcnt[i0], 1);
  int r1 = atomicAdd(&lcnt[i1], 1);
  __syncthreads();
  if (t < NEXP) sbase[t] = atomicAdd(&cnts2[t], lcnt[t]);
  __syncthreads();
  int p0 = offs[i0] + sbase[i0] + r0;
  int p1 = offs[i1] + sbase[i1] + r1;
  rowsC[p0] = row; gateC[p0] = g0;
  rowsC[p1] = row; gateC[p1] = g1;
}

// ---- shared 8-phase machinery (verified R9-R14) ----
#define G8_BAR() do { __builtin_amdgcn_s_barrier(); \
                      __builtin_amdgcn_sched_barrier(0); } while (0)
#define G8_VM4() asm volatile("s_waitcnt vmcnt(4)" ::: "memory")
#define G8_VM0() asm volatile("s_waitcnt vmcnt(0)" ::: "memory")
#define G8_LGKM0() do { asm volatile("s_waitcnt lgkmcnt(0)" ::: "memory"); \
                        __builtin_amdgcn_sched_barrier(0); } while (0)
#define G8_LGKM8() asm volatile("s_waitcnt lgkmcnt(8)" ::: "memory")

#define READ_A(aL, mfh, Af) do { \
  _Pragma("unroll") for (int mf = 0; mf < 4; ++mf) { \
    Af[mf][0] = *(const bf16x8*)&(aL)[((mfh)*4+mf)*1024 + aBase + swzC[0]]; \
    Af[mf][1] = *(const bf16x8*)&(aL)[((mfh)*4+mf)*1024 + aBase + swzC[1]]; \
  } } while (0)

#define READ_B(bL, nfh, Bf) do { \
  _Pragma("unroll") for (int nf = 0; nf < 2; ++nf) { \
    Bf[nf][0] = *(const bf16x8*)&(bL)[((nfh)*2+nf)*1024 + bBase + swzC[0]]; \
    Bf[nf][1] = *(const bf16x8*)&(bL)[((nfh)*2+nf)*1024 + bBase + swzC[1]]; \
  } } while (0)

#define MFMA_Q(mfh, nfh, Af, Bf) do { \
  __builtin_amdgcn_s_setprio(1); \
  _Pragma("unroll") for (int kk = 0; kk < 2; ++kk) \
  _Pragma("unroll") for (int mf = 0; mf < 4; ++mf) \
  _Pragma("unroll") for (int nf = 0; nf < 2; ++nf) \
    acc[(mfh)*4+mf][(nfh)*2+nf] = __builtin_amdgcn_mfma_f32_16x16x32_bf16( \
        Af[mf][kk], Bf[nf][kk], acc[(mfh)*4+mf][(nfh)*2+nf], 0, 0, 0); \
  __builtin_amdgcn_s_setprio(0); } while (0)

#define G8_KLOOP() do { \
  stB(0, 0); stB(0, 1); stA(0, 0); stA(0, 1); \
  stB(1, 0); stB(1, 1); \
  G8_VM4(); \
  G8_BAR(); \
  bf16x8 Af[4][2], Bf0[2][2], Bf1[2][2]; \
  const int numI = numK >> 1; \
  for (int it = 0; it < numI; ++it) { \
    const int t1 = 2 * it + 1, t2 = 2 * it + 2, t3 = 2 * it + 3; \
    const bool last = (t2 >= numK); \
    READ_A(aH[0], 0, Af); \
    READ_B(bH[0], 0, Bf0); \
    stA(t1, 0); \
    G8_LGKM8(); \
    G8_BAR(); \
    G8_LGKM0(); \
    MFMA_Q(0, 0, Af, Bf0); \
    G8_BAR(); \
    READ_B(bH[0], 1, Bf1); \
    stA(t1, 1); \
    G8_BAR(); \
    G8_LGKM0(); \
    MFMA_Q(0, 1, Af, Bf1); \
    G8_BAR(); \
    READ_A(aH[0], 1, Af); \
    if (!last) stB(t2, 0); \
    G8_BAR(); \
    G8_LGKM0(); \
    MFMA_Q(1, 1, Af, Bf1); \
    G8_BAR(); \
    if (!last) stB(t2, 1); \
    G8_BAR(); \
    MFMA_Q(1, 0, Af, Bf0); \
    if (last) { G8_VM0(); } else { G8_VM4(); } \
    G8_BAR(); \
    READ_A(aH[1], 0, Af); \
    READ_B(bH[1], 0, Bf0); \
    if (!last) stA(t2, 0); \
    G8_LGKM8(); \
    G8_BAR(); \
    G8_LGKM0(); \
    MFMA_Q(0, 0, Af, Bf0); \
    G8_BAR(); \
    READ_B(bH[1], 1, Bf1); \
    if (!last) stA(t2, 1); \
    G8_BAR(); \
    G8_LGKM0(); \
    MFMA_Q(0, 1, Af, Bf1); \
    G8_BAR(); \
    READ_A(aH[1], 1, Af); \
    if (t3 < numK) stB(t3, 0); \
    G8_BAR(); \
    G8_LGKM0(); \
    MFMA_Q(1, 1, Af, Bf1); \
    G8_BAR(); \
    if (t3 < numK) stB(t3, 1); \
    G8_BAR(); \
    MFMA_Q(1, 0, Af, Bf0); \
    if (!last) { G8_VM4(); } \
    G8_BAR(); \
  } \
} while (0)

// ============================================================================
// gemm8p_router (R15): 8-phase 256x256 router GEMM with FUSED LOGITS epilogue.
// Computes Hr = relu(xn @ r_w1 + b1) in registers and directly contracts with
// r_w2 [HR,8] -> atomicAdd(logits[m][e]). Eliminates the 64 MB HrB write, the
// 64 MB re-read, and the logits_kernel launch; precision strictly improves
// (no Hr->bf16 requantization). 128 KB LDS caps occupancy at 1 block/CU, so
// __launch_bounds__(512,1) frees the register budget for the epilogue.
// logits must be zeroed before launch (memset, stream-ordered).
// ============================================================================
__global__ __launch_bounds__(512, 1)
void gemm8p_router(const u16* __restrict__ A0, const u16* __restrict__ B0,
                   const float* __restrict__ b1, const float* __restrict__ w2,
                   float* __restrict__ logits)
{
  const int NT = HR / 256;   // 8
  const unsigned swz = xcd_swz(blockIdx.x, gridDim.x);
  const int mt = (int)(swz / (unsigned)NT);
  if (mt >= N_TOK / 256) return;
  const int m0 = mt * 256;
  const int n0 = (int)(swz % (unsigned)NT) * 256;

  __shared__ alignas(16) u16 As[2][2][128 * 64];
  __shared__ alignas(16) u16 Bs[2][2][128 * 64];

  const int t = threadIdx.x;
  const int numK = DIM >> 6;   // 16

  const u16* aP[2][2]; const u16* bP[2][2]; int dst[2];
#pragma unroll
  for (int j = 0; j < 2; ++j) {
    const int gdx = j * 512 + t;
    const int rw = gdx >> 3;
    const int cs = ((gdx & 7) ^ (rw & 7)) << 3;
    dst[j] = gdx * 8;
#pragma unroll
    for (int h = 0; h < 2; ++h) {
      aP[h][j] = A0 + (size_t)(m0 + h * 128 + rw) * DIM + cs;
      bP[h][j] = B0 + (size_t)(n0 + h * 128 + rw) * DIM + cs;
    }
  }
  auto stA = [&](int tile, int h) {
    async16(aP[h][0] + (size_t)tile * 64, &As[tile & 1][h][dst[0]]);
    async16(aP[h][1] + (size_t)tile * 64, &As[tile & 1][h][dst[1]]);
  };
  auto stB = [&](int tile, int h) {
    async16(bP[h][0] + (size_t)tile * 64, &Bs[tile & 1][h][dst[0]]);
    async16(bP[h][1] + (size_t)tile * 64, &Bs[tile & 1][h][dst[1]]);
  };

  const int lane = t & 63, wv = t >> 6;
  const int wr = wv >> 2, wc = wv & 3;
  const int fr = lane & 15, fq = lane >> 4;
  int swzC[2];
#pragma unroll
  for (int kk = 0; kk < 2; ++kk)
    swzC[kk] = ((kk * 4 + fq) ^ (fr & 7)) << 3;
  const int aBase = fr * 64;
  const int bBase = (wc & 1) * 4096 + fr * 64;
  const u16* aH[2] = { &As[0][wr][0], &As[1][wr][0] };
  const u16* bH[2] = { &Bs[0][wc >> 1][0], &Bs[1][wc >> 1][0] };

  f32x4 acc[8][4];
#pragma unroll
  for (int i = 0; i < 8; ++i)
#pragma unroll
    for (int j = 0; j < 4; ++j) acc[i][j] = (f32x4){0.f, 0.f, 0.f, 0.f};

  G8_KLOOP();

  // ---- epilogue: v = relu(acc + b1[n]); logits[m][e] += sum_n v * w2[n][e]
  float bv[4]; float w2v[4][8];
#pragma unroll
  for (int nf = 0; nf < 4; ++nf) {
    const int n = n0 + wc * 64 + nf * 16 + fr;
    bv[nf] = b1[n];
    const float4* wp = (const float4*)(w2 + (size_t)n * 8);
    float4 wa = wp[0], wb = wp[1];
    w2v[nf][0] = wa.x; w2v[nf][1] = wa.y; w2v[nf][2] = wa.z; w2v[nf][3] = wa.w;
    w2v[nf][4] = wb.x; w2v[nf][5] = wb.y; w2v[nf][6] = wb.z; w2v[nf][7] = wb.w;
  }
#pragma unroll
  for (int mf = 0; mf < 8; ++mf) {
    float pe[4][8];
#pragma unroll
    for (int r = 0; r < 4; ++r)
#pragma unroll
      for (int e = 0; e < 8; ++e) pe[r][e] = 0.f;
#pragma unroll
    for (int nf = 0; nf < 4; ++nf)
#pragma unroll
      for (int r = 0; r < 4; ++r) {
        const float v = fmaxf(acc[mf][nf][r] + bv[nf], 0.f);
#pragma unroll
        for (int e = 0; e < 8; ++e) pe[r][e] += v * w2v[nf][e];
      }
#pragma unroll
    for (int offx = 1; offx < 16; offx <<= 1)
#pragma unroll
      for (int r = 0; r < 4; ++r)
#pragma unroll
        for (int e = 0; e < 8; ++e)
          pe[r][e] += __shfl_xor(pe[r][e], offx, 64);
    if (fr == 0) {
#pragma unroll
      for (int r = 0; r < 4; ++r) {
        const int m = m0 + wr * 128 + mf * 16 + fq * 4 + r;
#pragma unroll
        for (int e = 0; e < 8; ++e)
          atomicAdd(&logits[(size_t)m * 8 + e], pe[r][e]);
      }
    }
  }
}

// ============================================================================
// moe_fused (R14-verified): persistent dual-GEMM with PER-XCD work queues.
// ============================================================================
__global__ __launch_bounds__(512, 1)
void moe_fused(const u16* __restrict__ xnhi, const u16* __restrict__ ew1t,
               const u16* __restrict__ ew2t,
               const int* __restrict__ counts, const int* __restrict__ offs,
               const int* __restrict__ tileOffs2,
               const int* __restrict__ rowsC, const float* __restrict__ gatesC,
               const float* __restrict__ e_b1, const float* __restrict__ e_b2,
               u16* __restrict__ Hbuf, float* __restrict__ out,
               int* __restrict__ qc, int* __restrict__ ready)
{
  constexpr int NT1 = HID / 256;            // 16
  constexpr int NT2 = DIM / 256;            // 4
  constexpr int W1 = NT1 * MAXMT2;          // 2176
  constexpr int CHA = W1 / 8;               // 272
  constexpr int CHB = (NT2 * MAXMT2) / 8;   // 68

  __shared__ alignas(16) u16 As[2][2][128 * 64];
  __shared__ alignas(16) u16 Bs[2][2][128 * 64];
  __shared__ int sh_w;

  const int t = threadIdx.x;
  const int cls = (int)(blockIdx.x & 7);
  const int lane = t & 63, wv = t >> 6;
  const int wr = wv >> 2, wc = wv & 3;
  const int fr = lane & 15, fq = lane >> 4;
  int swzC[2];
#pragma unroll
  for (int kk = 0; kk < 2; ++kk)
    swzC[kk] = ((kk * 4 + fq) ^ (fr & 7)) << 3;
  const int aBase = fr * 64;
  const int bBase = (wc & 1) * 4096 + fr * 64;
  const u16* aH[2] = { &As[0][wr][0], &As[1][wr][0] };
  const u16* bH[2] = { &Bs[0][wc >> 1][0], &Bs[1][wc >> 1][0] };

  for (;;) {
    __syncthreads();                        // LDS + sh_w reuse fence
    if (t == 0) {
      int enc = -1;
      for (int k = 0; k < 8 && enc < 0; ++k) {
        const int v = (cls + k) & 7;
        int w = atomicAdd(&qc[v], 1);
        if (w < CHA) { enc = v * CHA + w; break; }
        w = atomicAdd(&qc[8 + v], 1);
        if (w < CHB) { enc = W1 + v * CHB + w; break; }
      }
      sh_w = enc;
    }
    __syncthreads();
    const int w = sh_w;
    if (w < 0) return;
    const bool isG1 = (w < W1);
    const int wl = isG1 ? w : (w - W1);
    const int NT = isG1 ? NT1 : NT2;
    const int mt = wl / NT;
    if (mt >= tileOffs2[NEXP]) continue;
    int e = 0;
#pragma unroll
    for (int i = 1; i < NEXP; ++i) if (tileOffs2[i] <= mt) e = i;
    const int m0 = (mt - tileOffs2[e]) * 256;
    const int Mq = counts[e];
    if (m0 >= Mq) continue;
    const int off = offs[e];
    const int n0 = (wl % NT) * 256;

    if (!isG1) {
      if (t == 0) {
        while (__hip_atomic_load(ready + mt, __ATOMIC_ACQUIRE,
                                 __HIP_MEMORY_SCOPE_AGENT) < NT1)
          __builtin_amdgcn_s_sleep(8);
      }
      __syncthreads();
    }

    const int lda = isG1 ? DIM : HID;       // = ldb
    const int numK = (isG1 ? DIM : HID) >> 6;
    const u16* Asrc = isG1 ? xnhi : Hbuf;
    const u16* B = isG1 ? (ew1t + (size_t)e * HID * DIM)
                        : (ew2t + (size_t)e * DIM * HID);
    const float* bi = isG1 ? (e_b1 + (size_t)e * HID)
                           : (e_b2 + (size_t)e * DIM);
    const int* rows = rowsC + off;

    const u16* aP[2][2]; const u16* bP[2][2]; int dst[2];
#pragma unroll
    for (int j = 0; j < 2; ++j) {
      const int gdx = j * 512 + t;
      const int rw = gdx >> 3;
      const int cs = ((gdx & 7) ^ (rw & 7)) << 3;
      dst[j] = gdx * 8;
#pragma unroll
      for (int h = 0; h < 2; ++h) {
        const int grow = m0 + h * 128 + rw;
        const int amc = grow < Mq ? grow : (Mq - 1);
        const size_t agr = isG1 ? (size_t)rows[amc] : (size_t)(off + amc);
        aP[h][j] = Asrc + agr * lda + cs;
        bP[h][j] = B + (size_t)(n0 + h * 128 + rw) * lda + cs;
      }
    }
    auto stA = [&](int tile, int h) {
      async16(aP[h][0] + (size_t)tile * 64, &As[tile & 1][h][dst[0]]);
      async16(aP[h][1] + (size_t)tile * 64, &As[tile & 1][h][dst[1]]);
    };
    auto stB = [&](int tile, int h) {
      async16(bP[h][0] + (size_t)tile * 64, &Bs[tile & 1][h][dst[0]]);
      async16(bP[h][1] + (size_t)tile * 64, &Bs[tile & 1][h][dst[1]]);
    };

    f32x4 acc[8][4];
#pragma unroll
    for (int i = 0; i < 8; ++i)
#pragma unroll
      for (int j = 0; j < 4; ++j) acc[i][j] = (f32x4){0.f, 0.f, 0.f, 0.f};

    // drain prior item's stores/atomics so counted vmcnt stays exact
    asm volatile("s_waitcnt vmcnt(0)" ::: "memory");

    G8_KLOOP();

    // ---- epilogue ----
    float bv[4];
#pragma unroll
    for (int nf = 0; nf < 4; ++nf) bv[nf] = bi[n0 + wc * 64 + nf * 16 + fr];

    if (isG1) {
#pragma unroll
      for (int mf = 0; mf < 8; ++mf)
#pragma unroll
        for (int r = 0; r < 4; ++r) {
          const int m = m0 + wr * 128 + mf * 16 + fq * 4 + r;
          if (m < Mq) {
#pragma unroll
            for (int nf = 0; nf < 4; ++nf) {
              const int n = n0 + wc * 64 + nf * 16 + fr;
              Hbuf[(size_t)(off + m) * HID + n] =
                  f2bf(fmaxf(acc[mf][nf][r] + bv[nf], 0.f));
            }
          }
        }
      __syncthreads();   // drains every thread's stores (waitcnt pre-barrier)
      if (t == 0)
        __hip_atomic_fetch_add(ready + mt, 1, __ATOMIC_RELEASE,
                               __HIP_MEMORY_SCOPE_AGENT);
    } else {
#pragma unroll
      for (int mf = 0; mf < 8; ++mf)
#pragma unroll
        for (int r = 0; r < 4; ++r) {
          const int m = m0 + wr * 128 + mf * 16 + fq * 4 + r;
          if (m < Mq) {
            const size_t orow = (size_t)rows[m];
            const float g = gatesC[off + m];
#pragma unroll
            for (int nf = 0; nf < 4; ++nf) {
              const int n = n0 + wc * 64 + nf * 16 + fr;
              atomicAdd(&out[orow * DIM + n], g * (acc[mf][nf][r] + bv[nf]));
            }
          }
        }
    }
  }
}

// ---------------- GEMM: legacy 128x128 kernel (fix-GEMM, fallback) ----------
template<bool SPLIT, int EPI, bool GATHER>
__global__ __launch_bounds__(256, 2)
void gemm_bt(const u16* __restrict__ A0, const u16* __restrict__ A1,
             const u16* __restrict__ B0, const u16* __restrict__ B1,
             int lda, int ldb, int K, int M,
             const int* __restrict__ counts, int expertArg,
             const int* __restrict__ offs,
             const int* __restrict__ rowsC, const float* __restrict__ gatesC,
             const float* __restrict__ bias,
             const float* __restrict__ w2, float* __restrict__ logits,
             u16* __restrict__ Cbf, float* __restrict__ Cf32, int ldc)
{
  int expert, m0, n0;
  if (counts == nullptr) {
    const unsigned nwg = gridDim.x * gridDim.y;
    const unsigned flat = blockIdx.y * gridDim.x + blockIdx.x;
    const unsigned swz = xcd_swz(flat, nwg);
    expert = expertArg;
    m0 = (int)(swz / gridDim.x) * 128;
    n0 = (int)(swz % gridDim.x) * 128;
  } else {
    expert = expertArg;
    m0 = blockIdx.y * 128;
    n0 = blockIdx.x * 128;
  }

  const int Mq = counts ? counts[expert] : M;
  if (m0 >= Mq) return;
  const int off = offs ? offs[expert] : 0;
  const int* rows = rowsC ? rowsC + off : nullptr;
  const float* gates = gatesC ? gatesC + off : nullptr;
  const u16* B = B0;
  const u16* Bl = SPLIT ? B1 : nullptr;
  const float* bi = bias;
  const int z = (int)blockIdx.z;
  const int zOff = z * K;

  __shared__ u16 As0[128 * 32], Bs0[128 * 32];
  __shared__ u16 As1[SPLIT ? 128 * 32 : 8], Bs1[SPLIT ? 128 * 32 : 8];

  const int t = threadIdx.x;
  size_t aoff[2]; int acodd[2]; size_t boff[2];
#pragma unroll
  for (int i = 0; i < 2; ++i) {
    int gdx = i * 256 + t;
    int ar = gdx >> 2, ac = (gdx & 3) * 8;
    int am = m0 + ar;
    int amc = am < Mq ? am : (Mq - 1);
    int agr = GATHER ? rows[amc] : amc;
    aoff[i] = (size_t)agr * lda + ac + zOff;
    boff[i] = (size_t)(n0 + ar) * ldb + ac + zOff;
    acodd[i] = gdx * 8;
  }

  f32x4 acc[4][4];
#pragma unroll
  for (int i = 0; i < 4; ++i)
#pragma unroll
    for (int j = 0; j < 4; ++j) acc[i][j] = (f32x4){0.f, 0.f, 0.f, 0.f};

  const int lane = t & 63, wv = t >> 6;
  const int wm = (wv >> 1) * 64, wn = (wv & 1) * 64;
  const int fr = lane & 15, fq = lane >> 4;

  for (int k0 = 0; k0 < K; k0 += 32) {
    __syncthreads();
#pragma unroll
    for (int i = 0; i < 2; ++i) {
      async16(A0 + aoff[i] + k0, &As0[acodd[i]]);
      async16(B + boff[i] + k0, &Bs0[acodd[i]]);
      if (SPLIT) {
        async16(A1 + aoff[i] + k0, &As1[acodd[i]]);
        async16(Bl + boff[i] + k0, &Bs1[acodd[i]]);
      }
    }
    __syncthreads();
    bf16x8 af[4], bfr[4], af1[4], bf1[4];
#pragma unroll
    for (int xi = 0; xi < 4; ++xi) {
      af[xi]  = *(const bf16x8*)&As0[(wm + xi * 16 + fr) * 32 + fq * 8];
      bfr[xi] = *(const bf16x8*)&Bs0[(wn + xi * 16 + fr) * 32 + fq * 8];
      if (SPLIT) {
        af1[xi] = *(const bf16x8*)&As1[(wm + xi * 16 + fr) * 32 + fq * 8];
        bf1[xi] = *(const bf16x8*)&Bs1[(wn + xi * 16 + fr) * 32 + fq * 8];
      }
    }
#pragma unroll
    for (int mt = 0; mt < 4; ++mt)
#pragma unroll
      for (int nt = 0; nt < 4; ++nt) {
        acc[mt][nt] = __builtin_amdgcn_mfma_f32_16x16x32_bf16(af[mt], bfr[nt], acc[mt][nt], 0, 0, 0);
        if (SPLIT) {
          acc[mt][nt] = __builtin_amdgcn_mfma_f32_16x16x32_bf16(af[mt], bf1[nt], acc[mt][nt], 0, 0, 0);
          acc[mt][nt] = __builtin_amdgcn_mfma_f32_16x16x32_bf16(af1[mt], bfr[nt], acc[mt][nt], 0, 0, 0);
        }
      }
  }

  if constexpr (EPI == 3) {
    float w2v[4][8]; float b1v[4];
#pragma unroll
    for (int nt = 0; nt < 4; ++nt) {
      const int n = n0 + wn + nt * 16 + fr;
      b1v[nt] = bi[n];
      const float4* wp = (const float4*)(w2 + (size_t)n * 8);
      float4 wa = wp[0], wb = wp[1];
      w2v[nt][0] = wa.x; w2v[nt][1] = wa.y; w2v[nt][2] = wa.z; w2v[nt][3] = wa.w;
      w2v[nt][4] = wb.x; w2v[nt][5] = wb.y; w2v[nt][6] = wb.z; w2v[nt][7] = wb.w;
    }
#pragma unroll
    for (int mt = 0; mt < 4; ++mt) {
      float pe[4][8];
#pragma unroll
      for (int r = 0; r < 4; ++r)
#pragma unroll
        for (int ee = 0; ee < 8; ++ee) pe[r][ee] = 0.f;
#pragma unroll
      for (int nt = 0; nt < 4; ++nt)
#pragma unroll
        for (int r = 0; r < 4; ++r) {
          float v = fmaxf(acc[mt][nt][r] + b1v[nt], 0.f);
#pragma unroll
          for (int ee = 0; ee < 8; ++ee) pe[r][ee] += v * w2v[nt][ee];
        }
#pragma unroll
      for (int offx = 1; offx < 16; offx <<= 1)
#pragma unroll
        for (int r = 0; r < 4; ++r)
#pragma unroll
          for (int ee = 0; ee < 8; ++ee)
            pe[r][ee] += __shfl_xor(pe[r][ee], offx, 64);
      if (fr == 0) {
#pragma unroll
        for (int r = 0; r < 4; ++r) {
          const int m = m0 + wm + mt * 16 + fq * 4 + r;
          if (m < Mq) {
            const int lrow = GATHER ? rows[m] : m;
#pragma unroll
            for (int ee = 0; ee < 8; ++ee)
              atomicAdd(&logits[(size_t)lrow * 8 + ee], pe[r][ee]);
          }
        }
      }
    }
    return;
  }

#pragma unroll
  for (int mt = 0; mt < 4; ++mt) {
#pragma unroll
    for (int nt = 0; nt < 4; ++nt) {
      const int n = n0 + wn + nt * 16 + fr;
      const float bvv = (z == 0) ? bi[n] : 0.f;
#pragma unroll
      for (int r = 0; r < 4; ++r) {
        const int m = m0 + wm + mt * 16 + fq * 4 + r;
        if (m < Mq) {
          float v = acc[mt][nt][r] + bvv;
          if constexpr (EPI == 1) {
            Cbf[(size_t)m * ldc + n] = f2bf(fmaxf(v, 0.f));
          } else {
            atomicAdd(&Cf32[(size_t)rows[m] * ldc + n], gates[m] * v);
          }
        }
      }
    }
  }
}

extern "C" void kernel_launch(void* const* d_in, const int* in_sizes, int n_in,
                              void* d_out, int out_size, void* d_ws, size_t ws_size,
                              hipStream_t stream)
{
  const float* x    = (const float*)d_in[0];
  const float* ln_g = (const float*)d_in[1];
  const float* ln_b = (const float*)d_in[2];
  const float* r_w1 = (const float*)d_in[3];
  const float* r_b1 = (const float*)d_in[4];
  const float* r_w2 = (const float*)d_in[5];
  const float* r_b2 = (const float*)d_in[6];
  const float* e_w1 = (const float*)d_in[7];
  const float* e_b1 = (const float*)d_in[8];
  const float* e_w2 = (const float*)d_in[9];
  const float* e_b2 = (const float*)d_in[10];
  float* out = (float*)d_out;

  char* ws = (char*)d_ws;
  const size_t MB = 1024ull * 1024ull;
  u16*   xnhi = (u16*)(ws);                 // 32 MB  [N, D] bf16
  u16*   xnlo = (u16*)(ws + 32 * MB);       // 32 MB
  u16*   rw1h = (u16*)(ws + 64 * MB);       // 4 MB   [HR, D] bf16
  u16*   rw1l = (u16*)(ws + 68 * MB);       // 4 MB
  u16*   ew1t = (u16*)(ws + 72 * MB);       // 64 MB  [E][H, D] bf16
  u16*   ew2t = (u16*)(ws + 136 * MB);      // 64 MB  [E][D, H] bf16
  float* logits = (float*)(ws + 200 * MB);                    // 512 KB [N, 8]
  int*   rowsC  = (int*)(ws + 200 * MB + 512 * 1024);         // 128 KB [2N]
  float* gateC  = (float*)(ws + 200 * MB + 640 * 1024);       // 128 KB [2N]
  int*   fixL   = (int*)(ws + 200 * MB + 768 * 1024);         // 64 KB  [N]
  int*   cntb   = (int*)(ws + 200 * MB + 832 * 1024);         // 256 B
  int*   cnts   = cntb;          // [8]
  int*   cnts2  = cntb + 8;      // [8]
  int*   offs   = cntb + 16;     // [9]
  int*   cntFix = cntb + 25;     // [1]
  int*   tileOffs  = cntb + 32;  // [9]
  int*   tileOffs2 = cntb + 48;  // [9]
  int*   qready = (int*)(ws + 200 * MB + 836 * 1024);  // 4 KB: qc[16] + ready
  int*   qc     = qready;
  int*   ready  = qready + 16;
  u16*   Hbuf = (u16*)(ws + 201 * MB);      // fused: 256 MB [2N, H]
  (void)in_sizes; (void)n_in; (void)out_size;

  const bool fused = ws_size >= 458ull * MB;

  hipMemsetAsync(cntb, 0, 256, stream);
  hipMemsetAsync(qready, 0, 4096, stream);
  hipMemsetAsync(logits, 0, 512 * 1024, stream);   // router atomics accumulate

  transpose_cvt<true ><<<dim3(HR / 64, DIM / 64, 1), 256, 0, stream>>>(r_w1, rw1h, rw1l, DIM, HR);
  transpose_cvt<false><<<dim3(HID / 64, DIM / 64, NEXP), 256, 0, stream>>>(e_w1, ew1t, nullptr, DIM, HID);
  transpose_cvt<false><<<dim3(DIM / 64, HID / 64, NEXP), 256, 0, stream>>>(e_w2, ew2t, nullptr, HID, DIM);

  ln_kernel<<<N_TOK, 256, 0, stream>>>(x, ln_g, ln_b, xnhi, xnlo, out);

  // router + fused logits: logits[m][e] = sum_n relu(xn@r_w1+b1)[m,n]*r_w2[n,e]
  gemm8p_router<<<dim3((HR / 256) * (N_TOK / 256)), 512, 0, stream>>>(
      xnhi, rw1h, r_b1, r_w2, logits);

  pass_flag<<<N_TOK / 256, 256, 0, stream>>>(logits, r_b2, fixL, cntFix);

  gemm_bt<true, 3, true><<<dim3(HR / 128, N_TOK / 128), 256, 0, stream>>>(
      xnhi, xnlo, rw1h, rw1l, DIM, DIM, DIM, N_TOK,
      cntFix, 0, nullptr, fixL, nullptr, r_b1, r_w2, logits,
      nullptr, nullptr, 0);

  pass_count<<<N_TOK / 256, 256, 0, stream>>>(logits, r_b2, cnts);
  scan_kernel<<<1, 64, 0, stream>>>(cnts, offs, tileOffs, tileOffs2);
  pass_scatter<<<N_TOK / 256, 256, 0, stream>>>(logits, r_b2, offs, cnts2, rowsC, gateC);

  if (fused) {
    // persistent dual-GEMM: per-XCD queues, fine-grained G1->G2 readiness
    moe_fused<<<dim3(256), 512, 0, stream>>>(
        xnhi, ew1t, ew2t, cnts, offs, tileOffs2, rowsC, gateC,
        e_b1, e_b2, Hbuf, out, qc, ready);
  } else {
    for (int e = 0; e < NEXP; ++e) {
      gemm_bt<false, 1, true><<<dim3(HID / 128, N_TOK / 128), 256, 0, stream>>>(
          xnhi, nullptr, ew1t + (size_t)e * HID * DIM, nullptr,
          DIM, DIM, DIM, N_TOK,
          cnts, e, offs, rowsC, nullptr, e_b1 + (size_t)e * HID, nullptr, nullptr,
          Hbuf, nullptr, HID);
      gemm_bt<false, 2, false><<<dim3(DIM / 128, N_TOK / 128, 2), 256, 0, stream>>>(
          Hbuf, nullptr, ew2t + (size_t)e * DIM * HID, nullptr,
          HID, HID, HID / 2, N_TOK,
          cnts, e, offs, rowsC, gateC, e_b2 + (size_t)e * DIM, nullptr, nullptr,
          nullptr, out, DIM);
    }
  }
}

// Round 16
// 1365.914 us; speedup vs baseline: 1.2782x; 1.2782x over previous
//
#include <hip/hip_runtime.h>
#include <cstdint>
#include <cstddef>

typedef unsigned short u16;
typedef __attribute__((ext_vector_type(8))) short bf16x8;
typedef __attribute__((ext_vector_type(4))) float f32x4;

#define N_TOK 16384
#define DIM   1024
#define HID   4096
#define NEXP  8
#define HR    2048
#define TAU   0.02f
#define MAXMT 264   // sum_e ceil(cnt[e]/128) bound (fix/fallback paths)
#define MAXMT2 136  // sum_e ceil(cnt[e]/256) bound (= 8 * 17)

__device__ __forceinline__ u16 f2bf(float f) {
  union { float f; uint32_t u; } x; x.f = f;
  uint32_t r = x.u + 0x7FFFu + ((x.u >> 16) & 1u);
  return (u16)(r >> 16);
}
__device__ __forceinline__ float bf2f(u16 u) {
  union { uint32_t u; float f; } x; x.u = ((uint32_t)u) << 16; return x.f;
}

__device__ __forceinline__ void async16(const void* g, const void* l) {
  auto gp = reinterpret_cast<const __attribute__((address_space(1))) uint32_t*>(
      reinterpret_cast<uintptr_t>(g));
  auto lp = reinterpret_cast<__attribute__((address_space(3))) uint32_t*>(
      reinterpret_cast<uintptr_t>(l));
  __builtin_amdgcn_global_load_lds(gp, lp, 16, 0, 0);
}

// bijective XCD-chunk remap (m204)
__device__ __forceinline__ unsigned xcd_swz(unsigned flat, unsigned nwg) {
  const unsigned xcd = flat & 7u, lid = flat >> 3;
  const unsigned q = nwg >> 3, r = nwg & 7u;
  return (xcd < r ? xcd * (q + 1u) : r * (q + 1u) + (xcd - r) * q) + lid;
}

// ---------------- transpose + fp32->bf16 convert, vectorized ----------------
template<bool SPLIT>
__global__ __launch_bounds__(256)
void transpose_cvt(const float* __restrict__ src, u16* __restrict__ hi,
                   u16* __restrict__ lo, int R, int C)
{
  __shared__ float tile[64][65];
  const size_t bofs = (size_t)blockIdx.z * R * C;
  src += bofs; hi += bofs; if (SPLIT) lo += bofs;
  const int t = threadIdx.x;
  const int c0 = blockIdx.x * 64, r0 = blockIdx.y * 64;
#pragma unroll
  for (int i = 0; i < 4; ++i) {
    const int idx = i * 256 + t;
    const int rr = idx >> 4;
    const int cc = (idx & 15) << 2;
    const float4 v = *(const float4*)(src + (size_t)(r0 + rr) * C + c0 + cc);
    tile[rr][cc] = v.x; tile[rr][cc + 1] = v.y;
    tile[rr][cc + 2] = v.z; tile[rr][cc + 3] = v.w;
  }
  __syncthreads();
#pragma unroll
  for (int i = 0; i < 4; ++i) {
    const int idx = i * 256 + t;
    const int oc = idx >> 4;
    const int rc = (idx & 15) << 2;
    float v0 = tile[rc][oc], v1 = tile[rc + 1][oc];
    float v2 = tile[rc + 2][oc], v3 = tile[rc + 3][oc];
    ushort4 h;
    h.x = f2bf(v0); h.y = f2bf(v1); h.z = f2bf(v2); h.w = f2bf(v3);
    const size_t o = (size_t)(c0 + oc) * R + r0 + rc;
    *(ushort4*)(hi + o) = h;
    if (SPLIT) {
      ushort4 l;
      l.x = f2bf(v0 - bf2f(h.x)); l.y = f2bf(v1 - bf2f(h.y));
      l.z = f2bf(v2 - bf2f(h.z)); l.w = f2bf(v3 - bf2f(h.w));
      *(ushort4*)(lo + o) = l;
    }
  }
}

// ---------------- LayerNorm -> xn_hi/xn_lo bf16, out = x (residual init) ----
__global__ __launch_bounds__(256)
void ln_kernel(const float* __restrict__ x, const float* __restrict__ g,
               const float* __restrict__ b, u16* __restrict__ xh,
               u16* __restrict__ xl, float* __restrict__ out)
{
  const int row = blockIdx.x;
  const int t = threadIdx.x;
  const float4 xv = ((const float4*)(x + (size_t)row * DIM))[t];
  float s = xv.x + xv.y + xv.z + xv.w;
  float q = xv.x * xv.x + xv.y * xv.y + xv.z * xv.z + xv.w * xv.w;
#pragma unroll
  for (int off = 32; off; off >>= 1) {
    s += __shfl_down(s, off, 64);
    q += __shfl_down(q, off, 64);
  }
  __shared__ float sm[8];
  __shared__ float mu_s, rs_s;
  const int lane = t & 63, wv = t >> 6;
  if (lane == 0) { sm[wv] = s; sm[wv + 4] = q; }
  __syncthreads();
  if (t == 0) {
    float S = sm[0] + sm[1] + sm[2] + sm[3];
    float Q = sm[4] + sm[5] + sm[6] + sm[7];
    float mu = S * (1.f / DIM);
    float var = Q * (1.f / DIM) - mu * mu;
    mu_s = mu; rs_s = rsqrtf(var + 1e-5f);
  }
  __syncthreads();
  const float mu = mu_s, rs = rs_s;
  const float4 gv = ((const float4*)g)[t];
  const float4 bv = ((const float4*)b)[t];
  float n0 = (xv.x - mu) * rs * gv.x + bv.x;
  float n1 = (xv.y - mu) * rs * gv.y + bv.y;
  float n2 = (xv.z - mu) * rs * gv.z + bv.z;
  float n3 = (xv.w - mu) * rs * gv.w + bv.w;
  ushort4 h, l;
  h.x = f2bf(n0); l.x = f2bf(n0 - bf2f(h.x));
  h.y = f2bf(n1); l.y = f2bf(n1 - bf2f(h.y));
  h.z = f2bf(n2); l.z = f2bf(n2 - bf2f(h.z));
  h.w = f2bf(n3); l.w = f2bf(n3 - bf2f(h.w));
  ((ushort4*)(xh + (size_t)row * DIM))[t] = h;
  ((ushort4*)(xl + (size_t)row * DIM))[t] = l;
  ((float4*)(out + (size_t)row * DIM))[t] = xv;
}

// ---------------- logits = Hr(bf16) @ w2 (fp32), one block per row ----------
__global__ __launch_bounds__(256)
void logits_kernel(const u16* __restrict__ HrB, const float* __restrict__ w2,
                   float* __restrict__ logits)
{
  const int row = blockIdx.x, t = threadIdx.x;
  const u16* h = HrB + (size_t)row * HR;
  const ushort4* hv = (const ushort4*)(h + t * 8);
  ushort4 h0 = hv[0], h1 = hv[1];
  u16 hh[8] = {h0.x, h0.y, h0.z, h0.w, h1.x, h1.y, h1.z, h1.w};
  float p[8] = {0, 0, 0, 0, 0, 0, 0, 0};
#pragma unroll
  for (int j = 0; j < 8; ++j) {
    const int col = t * 8 + j;
    const float v = bf2f(hh[j]);
    const float4* wp = (const float4*)(w2 + (size_t)col * 8);
    float4 a = wp[0], b = wp[1];
    p[0] += v * a.x; p[1] += v * a.y; p[2] += v * a.z; p[3] += v * a.w;
    p[4] += v * b.x; p[5] += v * b.y; p[6] += v * b.z; p[7] += v * b.w;
  }
#pragma unroll
  for (int off = 32; off; off >>= 1)
#pragma unroll
    for (int e = 0; e < 8; ++e) p[e] += __shfl_down(p[e], off, 64);
  __shared__ float sm[4][8];
  const int lane = t & 63, wv = t >> 6;
  if (lane == 0) {
#pragma unroll
    for (int e = 0; e < 8; ++e) sm[wv][e] = p[e];
  }
  __syncthreads();
  if (t < 8)
    logits[(size_t)row * 8 + t] = sm[0][t] + sm[1][t] + sm[2][t] + sm[3][t];
}

__device__ __forceinline__ void load_logits(const float* logits, const float* b2,
                                            int row, float l[8]) {
  const float4* lp = (const float4*)(logits + (size_t)row * 8);
  float4 a = lp[0], b = lp[1];
  l[0] = a.x + b2[0]; l[1] = a.y + b2[1]; l[2] = a.z + b2[2]; l[3] = a.w + b2[3];
  l[4] = b.x + b2[4]; l[5] = b.y + b2[5]; l[6] = b.z + b2[6]; l[7] = b.w + b2[7];
}
__device__ __forceinline__ void top2(const float l[8], int& i0, float& l0,
                                     int& i1, float& l1) {
  i0 = 0; l0 = l[0];
#pragma unroll
  for (int e = 1; e < 8; ++e) if (l[e] > l0) { l0 = l[e]; i0 = e; }
  i1 = -1; l1 = -1e30f;
#pragma unroll
  for (int e = 0; e < 8; ++e) if (e != i0 && l[e] > l1) { l1 = l[e]; i1 = e; }
}

// ---------------- pass1: flag ambiguous rows, zero their logits -------------
__global__ __launch_bounds__(256)
void pass_flag(float* __restrict__ logits, const float* __restrict__ b2,
               int* __restrict__ fixL, int* __restrict__ cntFix)
{
  __shared__ int lcnt;
  __shared__ int base;
  const int t = threadIdx.x;
  const int row = blockIdx.x * 256 + t;
  if (t == 0) lcnt = 0;
  float l[8]; load_logits(logits, b2, row, l);
  int i0, i1; float l0, l1;
  top2(l, i0, l0, i1, l1);
  float l2 = -1e30f;
#pragma unroll
  for (int e = 0; e < 8; ++e)
    if (e != i0 && e != i1 && l[e] > l2) l2 = l[e];
  const bool flag = (l1 - l2) < TAU;
  __syncthreads();
  int r = 0;
  if (flag) r = atomicAdd(&lcnt, 1);
  __syncthreads();
  if (t == 0) base = atomicAdd(cntFix, lcnt);
  __syncthreads();
  if (flag) {
    fixL[base + r] = row;
    float4 z = {0.f, 0.f, 0.f, 0.f};
    ((float4*)(logits + (size_t)row * 8))[0] = z;
    ((float4*)(logits + (size_t)row * 8))[1] = z;
  }
}

// ---------------- pass_count / scan / pass_scatter --------------------------
__global__ __launch_bounds__(256)
void pass_count(const float* __restrict__ logits, const float* __restrict__ b2,
                int* __restrict__ cnts)
{
  __shared__ int lcnt[NEXP];
  const int t = threadIdx.x;
  const int row = blockIdx.x * 256 + t;
  if (t < NEXP) lcnt[t] = 0;
  float l[8]; load_logits(logits, b2, row, l);
  int i0, i1; float l0, l1;
  top2(l, i0, l0, i1, l1);
  __syncthreads();
  atomicAdd(&lcnt[i0], 1);
  atomicAdd(&lcnt[i1], 1);
  __syncthreads();
  if (t < NEXP) atomicAdd(&cnts[t], lcnt[t]);
}

__global__ void scan_kernel(const int* __restrict__ cnts, int* __restrict__ offs,
                            int* __restrict__ tileOffs, int* __restrict__ tileOffs2)
{
  if (threadIdx.x == 0) {
    int s = 0, ts = 0, ts2 = 0;
#pragma unroll
    for (int e = 0; e < NEXP; ++e) {
      offs[e] = s; s += cnts[e];
      tileOffs[e] = ts; ts += (cnts[e] + 127) >> 7;
      tileOffs2[e] = ts2; ts2 += (cnts[e] + 255) >> 8;
    }
    offs[NEXP] = s;
    tileOffs[NEXP] = ts;
    tileOffs2[NEXP] = ts2;
  }
}

__global__ __launch_bounds__(256)
void pass_scatter(const float* __restrict__ logits, const float* __restrict__ b2,
                  const int* __restrict__ offs, int* __restrict__ cnts2,
                  int* __restrict__ rowsC, float* __restrict__ gateC)
{
  __shared__ int lcnt[NEXP];
  __shared__ int sbase[NEXP];
  const int t = threadIdx.x;
  const int row = blockIdx.x * 256 + t;
  if (t < NEXP) lcnt[t] = 0;
  float l[8]; load_logits(logits, b2, row, l);
  int i0, i1; float l0, l1;
  top2(l, i0, l0, i1, l1);
  float tt = expf(l1 - l0);            // <= 1
  float g0 = 1.f / (1.f + tt);
  float g1 = tt / (1.f + tt);
  __syncthreads();
  int r0 = atomicAdd(&lcnt[i0], 1);
  int r1 = atomicAdd(&lcnt[i1], 1);
  __syncthreads();
  if (t < NEXP) sbase[t] = atomicAdd(&cnts2[t], lcnt[t]);
  __syncthreads();
  int p0 = offs[i0] + sbase[i0] + r0;
  int p1 = offs[i1] + sbase[i1] + r1;
  rowsC[p0] = row; gateC[p0] = g0;
  rowsC[p1] = row; gateC[p1] = g1;
}

// ---- shared 8-phase machinery (verified R9-R14) ----
#define G8_BAR() do { __builtin_amdgcn_s_barrier(); \
                      __builtin_amdgcn_sched_barrier(0); } while (0)
#define G8_VM4() asm volatile("s_waitcnt vmcnt(4)" ::: "memory")
#define G8_VM0() asm volatile("s_waitcnt vmcnt(0)" ::: "memory")
#define G8_LGKM0() do { asm volatile("s_waitcnt lgkmcnt(0)" ::: "memory"); \
                        __builtin_amdgcn_sched_barrier(0); } while (0)
#define G8_LGKM8() asm volatile("s_waitcnt lgkmcnt(8)" ::: "memory")

#define READ_A(aL, mfh, Af) do { \
  _Pragma("unroll") for (int mf = 0; mf < 4; ++mf) { \
    Af[mf][0] = *(const bf16x8*)&(aL)[((mfh)*4+mf)*1024 + aBase + swzC[0]]; \
    Af[mf][1] = *(const bf16x8*)&(aL)[((mfh)*4+mf)*1024 + aBase + swzC[1]]; \
  } } while (0)

#define READ_B(bL, nfh, Bf) do { \
  _Pragma("unroll") for (int nf = 0; nf < 2; ++nf) { \
    Bf[nf][0] = *(const bf16x8*)&(bL)[((nfh)*2+nf)*1024 + bBase + swzC[0]]; \
    Bf[nf][1] = *(const bf16x8*)&(bL)[((nfh)*2+nf)*1024 + bBase + swzC[1]]; \
  } } while (0)

#define MFMA_Q(mfh, nfh, Af, Bf) do { \
  __builtin_amdgcn_s_setprio(1); \
  _Pragma("unroll") for (int kk = 0; kk < 2; ++kk) \
  _Pragma("unroll") for (int mf = 0; mf < 4; ++mf) \
  _Pragma("unroll") for (int nf = 0; nf < 2; ++nf) \
    acc[(mfh)*4+mf][(nfh)*2+nf] = __builtin_amdgcn_mfma_f32_16x16x32_bf16( \
        Af[mf][kk], Bf[nf][kk], acc[(mfh)*4+mf][(nfh)*2+nf], 0, 0, 0); \
  __builtin_amdgcn_s_setprio(0); } while (0)

#define G8_KLOOP() do { \
  stB(0, 0); stB(0, 1); stA(0, 0); stA(0, 1); \
  stB(1, 0); stB(1, 1); \
  G8_VM4(); \
  G8_BAR(); \
  bf16x8 Af[4][2], Bf0[2][2], Bf1[2][2]; \
  const int numI = numK >> 1; \
  for (int it = 0; it < numI; ++it) { \
    const int t1 = 2 * it + 1, t2 = 2 * it + 2, t3 = 2 * it + 3; \
    const bool last = (t2 >= numK); \
    READ_A(aH[0], 0, Af); \
    READ_B(bH[0], 0, Bf0); \
    stA(t1, 0); \
    G8_LGKM8(); \
    G8_BAR(); \
    G8_LGKM0(); \
    MFMA_Q(0, 0, Af, Bf0); \
    G8_BAR(); \
    READ_B(bH[0], 1, Bf1); \
    stA(t1, 1); \
    G8_BAR(); \
    G8_LGKM0(); \
    MFMA_Q(0, 1, Af, Bf1); \
    G8_BAR(); \
    READ_A(aH[0], 1, Af); \
    if (!last) stB(t2, 0); \
    G8_BAR(); \
    G8_LGKM0(); \
    MFMA_Q(1, 1, Af, Bf1); \
    G8_BAR(); \
    if (!last) stB(t2, 1); \
    G8_BAR(); \
    MFMA_Q(1, 0, Af, Bf0); \
    if (last) { G8_VM0(); } else { G8_VM4(); } \
    G8_BAR(); \
    READ_A(aH[1], 0, Af); \
    READ_B(bH[1], 0, Bf0); \
    if (!last) stA(t2, 0); \
    G8_LGKM8(); \
    G8_BAR(); \
    G8_LGKM0(); \
    MFMA_Q(0, 0, Af, Bf0); \
    G8_BAR(); \
    READ_B(bH[1], 1, Bf1); \
    if (!last) stA(t2, 1); \
    G8_BAR(); \
    G8_LGKM0(); \
    MFMA_Q(0, 1, Af, Bf1); \
    G8_BAR(); \
    READ_A(aH[1], 1, Af); \
    if (t3 < numK) stB(t3, 0); \
    G8_BAR(); \
    G8_LGKM0(); \
    MFMA_Q(1, 1, Af, Bf1); \
    G8_BAR(); \
    if (t3 < numK) stB(t3, 1); \
    G8_BAR(); \
    MFMA_Q(1, 0, Af, Bf0); \
    if (!last) { G8_VM4(); } \
    G8_BAR(); \
  } \
} while (0)

// ============================================================================
// gemm8p (R11-verified): 8-phase 256x256 dense GEMM — used for the ROUTER.
// ============================================================================
template<int EPI>
__global__ __launch_bounds__(512, 2)
void gemm8p(const u16* __restrict__ A0, const u16* __restrict__ B0,
            int lda, int ldb, int K, int NT, int Mdense,
            const float* __restrict__ bias,
            u16* __restrict__ Cbf, int ldc)
{
  const unsigned swz = xcd_swz(blockIdx.x, gridDim.x);
  const int mt = (int)(swz / (unsigned)NT);
  if (mt >= Mdense / 256) return;
  const int m0 = mt * 256, Mq = Mdense;
  const int n0 = (int)(swz % (unsigned)NT) * 256;
  const float* bi = bias;

  __shared__ alignas(16) u16 As[2][2][128 * 64];
  __shared__ alignas(16) u16 Bs[2][2][128 * 64];

  const int t = threadIdx.x;
  const int numK = K >> 6;

  const u16* aP[2][2]; const u16* bP[2][2]; int dst[2];
#pragma unroll
  for (int j = 0; j < 2; ++j) {
    const int gdx = j * 512 + t;
    const int rw = gdx >> 3;
    const int cs = ((gdx & 7) ^ (rw & 7)) << 3;
    dst[j] = gdx * 8;
#pragma unroll
    for (int h = 0; h < 2; ++h) {
      aP[h][j] = A0 + (size_t)(m0 + h * 128 + rw) * lda + cs;
      bP[h][j] = B0 + (size_t)(n0 + h * 128 + rw) * ldb + cs;
    }
  }
  auto stA = [&](int tile, int h) {
    async16(aP[h][0] + (size_t)tile * 64, &As[tile & 1][h][dst[0]]);
    async16(aP[h][1] + (size_t)tile * 64, &As[tile & 1][h][dst[1]]);
  };
  auto stB = [&](int tile, int h) {
    async16(bP[h][0] + (size_t)tile * 64, &Bs[tile & 1][h][dst[0]]);
    async16(bP[h][1] + (size_t)tile * 64, &Bs[tile & 1][h][dst[1]]);
  };

  const int lane = t & 63, wv = t >> 6;
  const int wr = wv >> 2, wc = wv & 3;
  const int fr = lane & 15, fq = lane >> 4;
  int swzC[2];
#pragma unroll
  for (int kk = 0; kk < 2; ++kk)
    swzC[kk] = ((kk * 4 + fq) ^ (fr & 7)) << 3;
  const int aBase = fr * 64;
  const int bBase = (wc & 1) * 4096 + fr * 64;
  const u16* aH[2] = { &As[0][wr][0], &As[1][wr][0] };
  const u16* bH[2] = { &Bs[0][wc >> 1][0], &Bs[1][wc >> 1][0] };

  f32x4 acc[8][4];
#pragma unroll
  for (int i = 0; i < 8; ++i)
#pragma unroll
    for (int j = 0; j < 4; ++j) acc[i][j] = (f32x4){0.f, 0.f, 0.f, 0.f};

  G8_KLOOP();

  float bv[4];
#pragma unroll
  for (int nf = 0; nf < 4; ++nf) bv[nf] = bi[n0 + wc * 64 + nf * 16 + fr];
#pragma unroll
  for (int mf = 0; mf < 8; ++mf)
#pragma unroll
    for (int r = 0; r < 4; ++r) {
      const int m = m0 + wr * 128 + mf * 16 + fq * 4 + r;
      if (m < Mq) {
#pragma unroll
        for (int nf = 0; nf < 4; ++nf) {
          const int n = n0 + wc * 64 + nf * 16 + fr;
          Cbf[(size_t)m * ldc + n] = f2bf(fmaxf(acc[mf][nf][r] + bv[nf], 0.f));
        }
      }
    }
}

// ============================================================================
// moe_fused (R14-verified): persistent dual-GEMM with PER-XCD work queues.
// class c = blockIdx.x & 7; qc[c]: G1 items [272c,272c+272) (mt in [17c,17c+17),
// nt-fastest); qc[8+c]: G2 items [68c,68c+68) (same mt range -> deps in-class).
// Pop order: own-A, own-B, then steal (victim A then B). Deadlock-free; work-
// conserving. Readiness: agent-scope RELEASE add / ACQUIRE spin. vmcnt(0)
// drain before each item keeps the counted schedule exact.
// ============================================================================
__global__ __launch_bounds__(512, 1)
void moe_fused(const u16* __restrict__ xnhi, const u16* __restrict__ ew1t,
               const u16* __restrict__ ew2t,
               const int* __restrict__ counts, const int* __restrict__ offs,
               const int* __restrict__ tileOffs2,
               const int* __restrict__ rowsC, const float* __restrict__ gatesC,
               const float* __restrict__ e_b1, const float* __restrict__ e_b2,
               u16* __restrict__ Hbuf, float* __restrict__ out,
               int* __restrict__ qc, int* __restrict__ ready)
{
  constexpr int NT1 = HID / 256;            // 16
  constexpr int NT2 = DIM / 256;            // 4
  constexpr int W1 = NT1 * MAXMT2;          // 2176
  constexpr int CHA = W1 / 8;               // 272
  constexpr int CHB = (NT2 * MAXMT2) / 8;   // 68

  __shared__ alignas(16) u16 As[2][2][128 * 64];
  __shared__ alignas(16) u16 Bs[2][2][128 * 64];
  __shared__ int sh_w;

  const int t = threadIdx.x;
  const int cls = (int)(blockIdx.x & 7);
  const int lane = t & 63, wv = t >> 6;
  const int wr = wv >> 2, wc = wv & 3;
  const int fr = lane & 15, fq = lane >> 4;
  int swzC[2];
#pragma unroll
  for (int kk = 0; kk < 2; ++kk)
    swzC[kk] = ((kk * 4 + fq) ^ (fr & 7)) << 3;
  const int aBase = fr * 64;
  const int bBase = (wc & 1) * 4096 + fr * 64;
  const u16* aH[2] = { &As[0][wr][0], &As[1][wr][0] };
  const u16* bH[2] = { &Bs[0][wc >> 1][0], &Bs[1][wc >> 1][0] };

  for (;;) {
    __syncthreads();                        // LDS + sh_w reuse fence
    if (t == 0) {
      int enc = -1;
      for (int k = 0; k < 8 && enc < 0; ++k) {
        const int v = (cls + k) & 7;
        int w = atomicAdd(&qc[v], 1);
        if (w < CHA) { enc = v * CHA + w; break; }
        w = atomicAdd(&qc[8 + v], 1);
        if (w < CHB) { enc = W1 + v * CHB + w; break; }
      }
      sh_w = enc;
    }
    __syncthreads();
    const int w = sh_w;
    if (w < 0) return;
    const bool isG1 = (w < W1);
    const int wl = isG1 ? w : (w - W1);
    const int NT = isG1 ? NT1 : NT2;
    const int mt = wl / NT;
    if (mt >= tileOffs2[NEXP]) continue;
    int e = 0;
#pragma unroll
    for (int i = 1; i < NEXP; ++i) if (tileOffs2[i] <= mt) e = i;
    const int m0 = (mt - tileOffs2[e]) * 256;
    const int Mq = counts[e];
    if (m0 >= Mq) continue;
    const int off = offs[e];
    const int n0 = (wl % NT) * 256;

    if (!isG1) {
      if (t == 0) {
        while (__hip_atomic_load(ready + mt, __ATOMIC_ACQUIRE,
                                 __HIP_MEMORY_SCOPE_AGENT) < NT1)
          __builtin_amdgcn_s_sleep(8);
      }
      __syncthreads();
    }

    const int lda = isG1 ? DIM : HID;       // = ldb
    const int numK = (isG1 ? DIM : HID) >> 6;
    const u16* Asrc = isG1 ? xnhi : Hbuf;
    const u16* B = isG1 ? (ew1t + (size_t)e * HID * DIM)
                        : (ew2t + (size_t)e * DIM * HID);
    const float* bi = isG1 ? (e_b1 + (size_t)e * HID)
                           : (e_b2 + (size_t)e * DIM);
    const int* rows = rowsC + off;

    const u16* aP[2][2]; const u16* bP[2][2]; int dst[2];
#pragma unroll
    for (int j = 0; j < 2; ++j) {
      const int gdx = j * 512 + t;
      const int rw = gdx >> 3;
      const int cs = ((gdx & 7) ^ (rw & 7)) << 3;
      dst[j] = gdx * 8;
#pragma unroll
      for (int h = 0; h < 2; ++h) {
        const int grow = m0 + h * 128 + rw;
        const int amc = grow < Mq ? grow : (Mq - 1);
        const size_t agr = isG1 ? (size_t)rows[amc] : (size_t)(off + amc);
        aP[h][j] = Asrc + agr * lda + cs;
        bP[h][j] = B + (size_t)(n0 + h * 128 + rw) * lda + cs;
      }
    }
    auto stA = [&](int tile, int h) {
      async16(aP[h][0] + (size_t)tile * 64, &As[tile & 1][h][dst[0]]);
      async16(aP[h][1] + (size_t)tile * 64, &As[tile & 1][h][dst[1]]);
    };
    auto stB = [&](int tile, int h) {
      async16(bP[h][0] + (size_t)tile * 64, &Bs[tile & 1][h][dst[0]]);
      async16(bP[h][1] + (size_t)tile * 64, &Bs[tile & 1][h][dst[1]]);
    };

    f32x4 acc[8][4];
#pragma unroll
    for (int i = 0; i < 8; ++i)
#pragma unroll
      for (int j = 0; j < 4; ++j) acc[i][j] = (f32x4){0.f, 0.f, 0.f, 0.f};

    // drain prior item's stores/atomics so counted vmcnt stays exact
    asm volatile("s_waitcnt vmcnt(0)" ::: "memory");

    G8_KLOOP();

    // ---- epilogue ----
    float bv[4];
#pragma unroll
    for (int nf = 0; nf < 4; ++nf) bv[nf] = bi[n0 + wc * 64 + nf * 16 + fr];

    if (isG1) {
#pragma unroll
      for (int mf = 0; mf < 8; ++mf)
#pragma unroll
        for (int r = 0; r < 4; ++r) {
          const int m = m0 + wr * 128 + mf * 16 + fq * 4 + r;
          if (m < Mq) {
#pragma unroll
            for (int nf = 0; nf < 4; ++nf) {
              const int n = n0 + wc * 64 + nf * 16 + fr;
              Hbuf[(size_t)(off + m) * HID + n] =
                  f2bf(fmaxf(acc[mf][nf][r] + bv[nf], 0.f));
            }
          }
        }
      __syncthreads();   // drains every thread's stores (waitcnt pre-barrier)
      if (t == 0)
        __hip_atomic_fetch_add(ready + mt, 1, __ATOMIC_RELEASE,
                               __HIP_MEMORY_SCOPE_AGENT);
    } else {
#pragma unroll
      for (int mf = 0; mf < 8; ++mf)
#pragma unroll
        for (int r = 0; r < 4; ++r) {
          const int m = m0 + wr * 128 + mf * 16 + fq * 4 + r;
          if (m < Mq) {
            const size_t orow = (size_t)rows[m];
            const float g = gatesC[off + m];
#pragma unroll
            for (int nf = 0; nf < 4; ++nf) {
              const int n = n0 + wc * 64 + nf * 16 + fr;
              atomicAdd(&out[orow * DIM + n], g * (acc[mf][nf][r] + bv[nf]));
            }
          }
        }
    }
  }
}

// ---------------- GEMM: legacy 128x128 kernel (fix-GEMM, fallback) ----------
template<bool SPLIT, int EPI, bool GATHER>
__global__ __launch_bounds__(256, 2)
void gemm_bt(const u16* __restrict__ A0, const u16* __restrict__ A1,
             const u16* __restrict__ B0, const u16* __restrict__ B1,
             int lda, int ldb, int K, int M,
             const int* __restrict__ counts, int expertArg,
             const int* __restrict__ offs,
             const int* __restrict__ rowsC, const float* __restrict__ gatesC,
             const float* __restrict__ bias,
             const float* __restrict__ w2, float* __restrict__ logits,
             u16* __restrict__ Cbf, float* __restrict__ Cf32, int ldc)
{
  int expert, m0, n0;
  if (counts == nullptr) {
    const unsigned nwg = gridDim.x * gridDim.y;
    const unsigned flat = blockIdx.y * gridDim.x + blockIdx.x;
    const unsigned swz = xcd_swz(flat, nwg);
    expert = expertArg;
    m0 = (int)(swz / gridDim.x) * 128;
    n0 = (int)(swz % gridDim.x) * 128;
  } else {
    expert = expertArg;
    m0 = blockIdx.y * 128;
    n0 = blockIdx.x * 128;
  }

  const int Mq = counts ? counts[expert] : M;
  if (m0 >= Mq) return;
  const int off = offs ? offs[expert] : 0;
  const int* rows = rowsC ? rowsC + off : nullptr;
  const float* gates = gatesC ? gatesC + off : nullptr;
  const u16* B = B0;
  const u16* Bl = SPLIT ? B1 : nullptr;
  const float* bi = bias;
  const int z = (int)blockIdx.z;
  const int zOff = z * K;

  __shared__ u16 As0[128 * 32], Bs0[128 * 32];
  __shared__ u16 As1[SPLIT ? 128 * 32 : 8], Bs1[SPLIT ? 128 * 32 : 8];

  const int t = threadIdx.x;
  size_t aoff[2]; int acodd[2]; size_t boff[2];
#pragma unroll
  for (int i = 0; i < 2; ++i) {
    int gdx = i * 256 + t;
    int ar = gdx >> 2, ac = (gdx & 3) * 8;
    int am = m0 + ar;
    int amc = am < Mq ? am : (Mq - 1);
    int agr = GATHER ? rows[amc] : amc;
    aoff[i] = (size_t)agr * lda + ac + zOff;
    boff[i] = (size_t)(n0 + ar) * ldb + ac + zOff;
    acodd[i] = gdx * 8;
  }

  f32x4 acc[4][4];
#pragma unroll
  for (int i = 0; i < 4; ++i)
#pragma unroll
    for (int j = 0; j < 4; ++j) acc[i][j] = (f32x4){0.f, 0.f, 0.f, 0.f};

  const int lane = t & 63, wv = t >> 6;
  const int wm = (wv >> 1) * 64, wn = (wv & 1) * 64;
  const int fr = lane & 15, fq = lane >> 4;

  for (int k0 = 0; k0 < K; k0 += 32) {
    __syncthreads();
#pragma unroll
    for (int i = 0; i < 2; ++i) {
      async16(A0 + aoff[i] + k0, &As0[acodd[i]]);
      async16(B + boff[i] + k0, &Bs0[acodd[i]]);
      if (SPLIT) {
        async16(A1 + aoff[i] + k0, &As1[acodd[i]]);
        async16(Bl + boff[i] + k0, &Bs1[acodd[i]]);
      }
    }
    __syncthreads();
    bf16x8 af[4], bfr[4], af1[4], bf1[4];
#pragma unroll
    for (int xi = 0; xi < 4; ++xi) {
      af[xi]  = *(const bf16x8*)&As0[(wm + xi * 16 + fr) * 32 + fq * 8];
      bfr[xi] = *(const bf16x8*)&Bs0[(wn + xi * 16 + fr) * 32 + fq * 8];
      if (SPLIT) {
        af1[xi] = *(const bf16x8*)&As1[(wm + xi * 16 + fr) * 32 + fq * 8];
        bf1[xi] = *(const bf16x8*)&Bs1[(wn + xi * 16 + fr) * 32 + fq * 8];
      }
    }
#pragma unroll
    for (int mt = 0; mt < 4; ++mt)
#pragma unroll
      for (int nt = 0; nt < 4; ++nt) {
        acc[mt][nt] = __builtin_amdgcn_mfma_f32_16x16x32_bf16(af[mt], bfr[nt], acc[mt][nt], 0, 0, 0);
        if (SPLIT) {
          acc[mt][nt] = __builtin_amdgcn_mfma_f32_16x16x32_bf16(af[mt], bf1[nt], acc[mt][nt], 0, 0, 0);
          acc[mt][nt] = __builtin_amdgcn_mfma_f32_16x16x32_bf16(af1[mt], bfr[nt], acc[mt][nt], 0, 0, 0);
        }
      }
  }

  if constexpr (EPI == 3) {
    float w2v[4][8]; float b1v[4];
#pragma unroll
    for (int nt = 0; nt < 4; ++nt) {
      const int n = n0 + wn + nt * 16 + fr;
      b1v[nt] = bi[n];
      const float4* wp = (const float4*)(w2 + (size_t)n * 8);
      float4 wa = wp[0], wb = wp[1];
      w2v[nt][0] = wa.x; w2v[nt][1] = wa.y; w2v[nt][2] = wa.z; w2v[nt][3] = wa.w;
      w2v[nt][4] = wb.x; w2v[nt][5] = wb.y; w2v[nt][6] = wb.z; w2v[nt][7] = wb.w;
    }
#pragma unroll
    for (int mt = 0; mt < 4; ++mt) {
      float pe[4][8];
#pragma unroll
      for (int r = 0; r < 4; ++r)
#pragma unroll
        for (int ee = 0; ee < 8; ++ee) pe[r][ee] = 0.f;
#pragma unroll
      for (int nt = 0; nt < 4; ++nt)
#pragma unroll
        for (int r = 0; r < 4; ++r) {
          float v = fmaxf(acc[mt][nt][r] + b1v[nt], 0.f);
#pragma unroll
          for (int ee = 0; ee < 8; ++ee) pe[r][ee] += v * w2v[nt][ee];
        }
#pragma unroll
      for (int offx = 1; offx < 16; offx <<= 1)
#pragma unroll
        for (int r = 0; r < 4; ++r)
#pragma unroll
          for (int ee = 0; ee < 8; ++ee)
            pe[r][ee] += __shfl_xor(pe[r][ee], offx, 64);
      if (fr == 0) {
#pragma unroll
        for (int r = 0; r < 4; ++r) {
          const int m = m0 + wm + mt * 16 + fq * 4 + r;
          if (m < Mq) {
            const int lrow = GATHER ? rows[m] : m;
#pragma unroll
            for (int ee = 0; ee < 8; ++ee)
              atomicAdd(&logits[(size_t)lrow * 8 + ee], pe[r][ee]);
          }
        }
      }
    }
    return;
  }

#pragma unroll
  for (int mt = 0; mt < 4; ++mt) {
#pragma unroll
    for (int nt = 0; nt < 4; ++nt) {
      const int n = n0 + wn + nt * 16 + fr;
      const float bvv = (z == 0) ? bi[n] : 0.f;
#pragma unroll
      for (int r = 0; r < 4; ++r) {
        const int m = m0 + wm + mt * 16 + fq * 4 + r;
        if (m < Mq) {
          float v = acc[mt][nt][r] + bvv;
          if constexpr (EPI == 1) {
            Cbf[(size_t)m * ldc + n] = f2bf(fmaxf(v, 0.f));
          } else {
            atomicAdd(&Cf32[(size_t)rows[m] * ldc + n], gates[m] * v);
          }
        }
      }
    }
  }
}

extern "C" void kernel_launch(void* const* d_in, const int* in_sizes, int n_in,
                              void* d_out, int out_size, void* d_ws, size_t ws_size,
                              hipStream_t stream)
{
  const float* x    = (const float*)d_in[0];
  const float* ln_g = (const float*)d_in[1];
  const float* ln_b = (const float*)d_in[2];
  const float* r_w1 = (const float*)d_in[3];
  const float* r_b1 = (const float*)d_in[4];
  const float* r_w2 = (const float*)d_in[5];
  const float* r_b2 = (const float*)d_in[6];
  const float* e_w1 = (const float*)d_in[7];
  const float* e_b1 = (const float*)d_in[8];
  const float* e_w2 = (const float*)d_in[9];
  const float* e_b2 = (const float*)d_in[10];
  float* out = (float*)d_out;

  char* ws = (char*)d_ws;
  const size_t MB = 1024ull * 1024ull;
  u16*   xnhi = (u16*)(ws);                 // 32 MB  [N, D] bf16
  u16*   xnlo = (u16*)(ws + 32 * MB);       // 32 MB
  u16*   rw1h = (u16*)(ws + 64 * MB);       // 4 MB   [HR, D] bf16
  u16*   rw1l = (u16*)(ws + 68 * MB);       // 4 MB
  u16*   ew1t = (u16*)(ws + 72 * MB);       // 64 MB  [E][H, D] bf16
  u16*   ew2t = (u16*)(ws + 136 * MB);      // 64 MB  [E][D, H] bf16
  float* logits = (float*)(ws + 200 * MB);                    // 512 KB [N, 8]
  int*   rowsC  = (int*)(ws + 200 * MB + 512 * 1024);         // 128 KB [2N]
  float* gateC  = (float*)(ws + 200 * MB + 640 * 1024);       // 128 KB [2N]
  int*   fixL   = (int*)(ws + 200 * MB + 768 * 1024);         // 64 KB  [N]
  int*   cntb   = (int*)(ws + 200 * MB + 832 * 1024);         // 256 B
  int*   cnts   = cntb;          // [8]
  int*   cnts2  = cntb + 8;      // [8]
  int*   offs   = cntb + 16;     // [9]
  int*   cntFix = cntb + 25;     // [1]
  int*   tileOffs  = cntb + 32;  // [9]
  int*   tileOffs2 = cntb + 48;  // [9]
  int*   qready = (int*)(ws + 200 * MB + 836 * 1024);  // 4 KB: qc[16] + ready
  int*   qc     = qready;
  int*   ready  = qready + 16;
  u16*   Hbuf = (u16*)(ws + 201 * MB);      // fused: 256 MB [2N, H]; HrB aliases
  u16*   HrB  = Hbuf;                       // 64 MB [N, HR] bf16 (router hidden)
  (void)in_sizes; (void)n_in; (void)out_size;

  const bool fused = ws_size >= 458ull * MB;

  hipMemsetAsync(cntb, 0, 256, stream);
  hipMemsetAsync(qready, 0, 4096, stream);

  transpose_cvt<true ><<<dim3(HR / 64, DIM / 64, 1), 256, 0, stream>>>(r_w1, rw1h, rw1l, DIM, HR);
  transpose_cvt<false><<<dim3(HID / 64, DIM / 64, NEXP), 256, 0, stream>>>(e_w1, ew1t, nullptr, DIM, HID);
  transpose_cvt<false><<<dim3(DIM / 64, HID / 64, NEXP), 256, 0, stream>>>(e_w2, ew2t, nullptr, HID, DIM);

  ln_kernel<<<N_TOK, 256, 0, stream>>>(x, ln_g, ln_b, xnhi, xnlo, out);

  // router: HrB = bf16(relu(xn @ r_w1 + b1)) — 8-phase DENSE
  gemm8p<1><<<dim3((HR / 256) * (N_TOK / 256)), 512, 0, stream>>>(
      xnhi, rw1h, DIM, DIM, DIM, HR / 256, N_TOK, r_b1, HrB, HR);

  logits_kernel<<<N_TOK, 256, 0, stream>>>(HrB, r_w2, logits);

  pass_flag<<<N_TOK / 256, 256, 0, stream>>>(logits, r_b2, fixL, cntFix);

  gemm_bt<true, 3, true><<<dim3(HR / 128, N_TOK / 128), 256, 0, stream>>>(
      xnhi, xnlo, rw1h, rw1l, DIM, DIM, DIM, N_TOK,
      cntFix, 0, nullptr, fixL, nullptr, r_b1, r_w2, logits,
      nullptr, nullptr, 0);

  pass_count<<<N_TOK / 256, 256, 0, stream>>>(logits, r_b2, cnts);
  scan_kernel<<<1, 64, 0, stream>>>(cnts, offs, tileOffs, tileOffs2);
  pass_scatter<<<N_TOK / 256, 256, 0, stream>>>(logits, r_b2, offs, cnts2, rowsC, gateC);

  if (fused) {
    // persistent dual-GEMM: per-XCD queues, fine-grained G1->G2 readiness
    moe_fused<<<dim3(256), 512, 0, stream>>>(
        xnhi, ew1t, ew2t, cnts, offs, tileOffs2, rowsC, gateC,
        e_b1, e_b2, Hbuf, out, qc, ready);
  } else {
    for (int e = 0; e < NEXP; ++e) {
      gemm_bt<false, 1, true><<<dim3(HID / 128, N_TOK / 128), 256, 0, stream>>>(
          xnhi, nullptr, ew1t + (size_t)e * HID * DIM, nullptr,
          DIM, DIM, DIM, N_TOK,
          cnts, e, offs, rowsC, nullptr, e_b1 + (size_t)e * HID, nullptr, nullptr,
          Hbuf, nullptr, HID);
      gemm_bt<false, 2, false><<<dim3(DIM / 128, N_TOK / 128, 2), 256, 0, stream>>>(
          Hbuf, nullptr, ew2t + (size_t)e * DIM * HID, nullptr,
          HID, HID, HID / 2, N_TOK,
          cnts, e, offs, rowsC, gateC, e_b2 + (size_t)e * DIM, nullptr, nullptr,
          nullptr, out, DIM);
    }
  }
}

// Round 17
// 1354.705 us; speedup vs baseline: 1.2888x; 1.0083x over previous
//
#include <hip/hip_runtime.h>
#include <cstdint>
#include <cstddef>

typedef unsigned short u16;
typedef __attribute__((ext_vector_type(8))) short bf16x8;
typedef __attribute__((ext_vector_type(4))) float f32x4;

#define N_TOK 16384
#define DIM   1024
#define HID   4096
#define NEXP  8
#define HR    2048
#define TAU   0.02f
#define MAXMT 264   // sum_e ceil(cnt[e]/128) bound (fix/fallback paths)
#define MAXMT2 136  // sum_e ceil(cnt[e]/256) bound (= 8 * 17)

__device__ __forceinline__ u16 f2bf(float f) {
  union { float f; uint32_t u; } x; x.f = f;
  uint32_t r = x.u + 0x7FFFu + ((x.u >> 16) & 1u);
  return (u16)(r >> 16);
}
__device__ __forceinline__ float bf2f(u16 u) {
  union { uint32_t u; float f; } x; x.u = ((uint32_t)u) << 16; return x.f;
}

__device__ __forceinline__ void async16(const void* g, const void* l) {
  auto gp = reinterpret_cast<const __attribute__((address_space(1))) uint32_t*>(
      reinterpret_cast<uintptr_t>(g));
  auto lp = reinterpret_cast<__attribute__((address_space(3))) uint32_t*>(
      reinterpret_cast<uintptr_t>(l));
  __builtin_amdgcn_global_load_lds(gp, lp, 16, 0, 0);
}

// bijective XCD-chunk remap (m204)
__device__ __forceinline__ unsigned xcd_swz(unsigned flat, unsigned nwg) {
  const unsigned xcd = flat & 7u, lid = flat >> 3;
  const unsigned q = nwg >> 3, r = nwg & 7u;
  return (xcd < r ? xcd * (q + 1u) : r * (q + 1u) + (xcd - r) * q) + lid;
}

// ---------------- ALL transposes in ONE launch (R17) ------------------------
// Flat 16896-block grid: [0,512) r_w1 (SPLIT, hi/lo), [512,8704) e_w1 x8,
// [8704,16896) e_w2 x8. 64x64 tiles; float4 loads, ushort4 stores; LDS pitch
// 65 (<=2-way alias, free). Independent tiles -> zero-risk launch merge.
__global__ __launch_bounds__(256)
void transpose_all(const float* __restrict__ r_w1, u16* __restrict__ rw1h,
                   u16* __restrict__ rw1l,
                   const float* __restrict__ e_w1, u16* __restrict__ ew1t,
                   const float* __restrict__ e_w2, u16* __restrict__ ew2t)
{
  const int id = (int)blockIdx.x;
  const float* src; u16* hi; u16* lo = nullptr;
  int R, C, bx, by; bool split = false;
  if (id < 512) {
    split = true; src = r_w1; hi = rw1h; lo = rw1l;
    R = DIM; C = HR;
    bx = id & 31; by = id >> 5;               // C/64=32, R/64=16
  } else if (id < 8704) {
    const int j = id - 512, e = j >> 10, r = j & 1023;
    src = e_w1 + (size_t)e * DIM * HID; hi = ew1t + (size_t)e * HID * DIM;
    R = DIM; C = HID;
    bx = r & 63; by = r >> 6;                 // C/64=64, R/64=16
  } else {
    const int j = id - 8704, e = j >> 10, r = j & 1023;
    src = e_w2 + (size_t)e * HID * DIM; hi = ew2t + (size_t)e * DIM * HID;
    R = HID; C = DIM;
    bx = r & 15; by = r >> 4;                 // C/64=16, R/64=64
  }

  __shared__ float tile[64][65];
  const int t = threadIdx.x;
  const int c0 = bx * 64, r0 = by * 64;
#pragma unroll
  for (int i = 0; i < 4; ++i) {
    const int idx = i * 256 + t;
    const int rr = idx >> 4;
    const int cc = (idx & 15) << 2;
    const float4 v = *(const float4*)(src + (size_t)(r0 + rr) * C + c0 + cc);
    tile[rr][cc] = v.x; tile[rr][cc + 1] = v.y;
    tile[rr][cc + 2] = v.z; tile[rr][cc + 3] = v.w;
  }
  __syncthreads();
#pragma unroll
  for (int i = 0; i < 4; ++i) {
    const int idx = i * 256 + t;
    const int oc = idx >> 4;
    const int rc = (idx & 15) << 2;
    float v0 = tile[rc][oc], v1 = tile[rc + 1][oc];
    float v2 = tile[rc + 2][oc], v3 = tile[rc + 3][oc];
    ushort4 h;
    h.x = f2bf(v0); h.y = f2bf(v1); h.z = f2bf(v2); h.w = f2bf(v3);
    const size_t o = (size_t)(c0 + oc) * R + r0 + rc;
    *(ushort4*)(hi + o) = h;
    if (split) {
      ushort4 l;
      l.x = f2bf(v0 - bf2f(h.x)); l.y = f2bf(v1 - bf2f(h.y));
      l.z = f2bf(v2 - bf2f(h.z)); l.w = f2bf(v3 - bf2f(h.w));
      *(ushort4*)(lo + o) = l;
    }
  }
}

// ---------------- LayerNorm -> xn_hi/xn_lo bf16, out = x (residual init) ----
__global__ __launch_bounds__(256)
void ln_kernel(const float* __restrict__ x, const float* __restrict__ g,
               const float* __restrict__ b, u16* __restrict__ xh,
               u16* __restrict__ xl, float* __restrict__ out)
{
  const int row = blockIdx.x;
  const int t = threadIdx.x;
  const float4 xv = ((const float4*)(x + (size_t)row * DIM))[t];
  float s = xv.x + xv.y + xv.z + xv.w;
  float q = xv.x * xv.x + xv.y * xv.y + xv.z * xv.z + xv.w * xv.w;
#pragma unroll
  for (int off = 32; off; off >>= 1) {
    s += __shfl_down(s, off, 64);
    q += __shfl_down(q, off, 64);
  }
  __shared__ float sm[8];
  __shared__ float mu_s, rs_s;
  const int lane = t & 63, wv = t >> 6;
  if (lane == 0) { sm[wv] = s; sm[wv + 4] = q; }
  __syncthreads();
  if (t == 0) {
    float S = sm[0] + sm[1] + sm[2] + sm[3];
    float Q = sm[4] + sm[5] + sm[6] + sm[7];
    float mu = S * (1.f / DIM);
    float var = Q * (1.f / DIM) - mu * mu;
    mu_s = mu; rs_s = rsqrtf(var + 1e-5f);
  }
  __syncthreads();
  const float mu = mu_s, rs = rs_s;
  const float4 gv = ((const float4*)g)[t];
  const float4 bv = ((const float4*)b)[t];
  float n0 = (xv.x - mu) * rs * gv.x + bv.x;
  float n1 = (xv.y - mu) * rs * gv.y + bv.y;
  float n2 = (xv.z - mu) * rs * gv.z + bv.z;
  float n3 = (xv.w - mu) * rs * gv.w + bv.w;
  ushort4 h, l;
  h.x = f2bf(n0); l.x = f2bf(n0 - bf2f(h.x));
  h.y = f2bf(n1); l.y = f2bf(n1 - bf2f(h.y));
  h.z = f2bf(n2); l.z = f2bf(n2 - bf2f(h.z));
  h.w = f2bf(n3); l.w = f2bf(n3 - bf2f(h.w));
  ((ushort4*)(xh + (size_t)row * DIM))[t] = h;
  ((ushort4*)(xl + (size_t)row * DIM))[t] = l;
  ((float4*)(out + (size_t)row * DIM))[t] = xv;
}

// ---------------- logits = Hr(bf16) @ w2 (fp32), one block per row ----------
__global__ __launch_bounds__(256)
void logits_kernel(const u16* __restrict__ HrB, const float* __restrict__ w2,
                   float* __restrict__ logits)
{
  const int row = blockIdx.x, t = threadIdx.x;
  const u16* h = HrB + (size_t)row * HR;
  const ushort4* hv = (const ushort4*)(h + t * 8);
  ushort4 h0 = hv[0], h1 = hv[1];
  u16 hh[8] = {h0.x, h0.y, h0.z, h0.w, h1.x, h1.y, h1.z, h1.w};
  float p[8] = {0, 0, 0, 0, 0, 0, 0, 0};
#pragma unroll
  for (int j = 0; j < 8; ++j) {
    const int col = t * 8 + j;
    const float v = bf2f(hh[j]);
    const float4* wp = (const float4*)(w2 + (size_t)col * 8);
    float4 a = wp[0], b = wp[1];
    p[0] += v * a.x; p[1] += v * a.y; p[2] += v * a.z; p[3] += v * a.w;
    p[4] += v * b.x; p[5] += v * b.y; p[6] += v * b.z; p[7] += v * b.w;
  }
#pragma unroll
  for (int off = 32; off; off >>= 1)
#pragma unroll
    for (int e = 0; e < 8; ++e) p[e] += __shfl_down(p[e], off, 64);
  __shared__ float sm[4][8];
  const int lane = t & 63, wv = t >> 6;
  if (lane == 0) {
#pragma unroll
    for (int e = 0; e < 8; ++e) sm[wv][e] = p[e];
  }
  __syncthreads();
  if (t < 8)
    logits[(size_t)row * 8 + t] = sm[0][t] + sm[1][t] + sm[2][t] + sm[3][t];
}

__device__ __forceinline__ void load_logits(const float* logits, const float* b2,
                                            int row, float l[8]) {
  const float4* lp = (const float4*)(logits + (size_t)row * 8);
  float4 a = lp[0], b = lp[1];
  l[0] = a.x + b2[0]; l[1] = a.y + b2[1]; l[2] = a.z + b2[2]; l[3] = a.w + b2[3];
  l[4] = b.x + b2[4]; l[5] = b.y + b2[5]; l[6] = b.z + b2[6]; l[7] = b.w + b2[7];
}
__device__ __forceinline__ void top2(const float l[8], int& i0, float& l0,
                                     int& i1, float& l1) {
  i0 = 0; l0 = l[0];
#pragma unroll
  for (int e = 1; e < 8; ++e) if (l[e] > l0) { l0 = l[e]; i0 = e; }
  i1 = -1; l1 = -1e30f;
#pragma unroll
  for (int e = 0; e < 8; ++e) if (e != i0 && l[e] > l1) { l1 = l[e]; i1 = e; }
}

// ---------------- pass1: flag ambiguous rows, zero their logits -------------
__global__ __launch_bounds__(256)
void pass_flag(float* __restrict__ logits, const float* __restrict__ b2,
               int* __restrict__ fixL, int* __restrict__ cntFix)
{
  __shared__ int lcnt;
  __shared__ int base;
  const int t = threadIdx.x;
  const int row = blockIdx.x * 256 + t;
  if (t == 0) lcnt = 0;
  float l[8]; load_logits(logits, b2, row, l);
  int i0, i1; float l0, l1;
  top2(l, i0, l0, i1, l1);
  float l2 = -1e30f;
#pragma unroll
  for (int e = 0; e < 8; ++e)
    if (e != i0 && e != i1 && l[e] > l2) l2 = l[e];
  const bool flag = (l1 - l2) < TAU;
  __syncthreads();
  int r = 0;
  if (flag) r = atomicAdd(&lcnt, 1);
  __syncthreads();
  if (t == 0) base = atomicAdd(cntFix, lcnt);
  __syncthreads();
  if (flag) {
    fixL[base + r] = row;
    float4 z = {0.f, 0.f, 0.f, 0.f};
    ((float4*)(logits + (size_t)row * 8))[0] = z;
    ((float4*)(logits + (size_t)row * 8))[1] = z;
  }
}

// ---------------- pass_count / pass_scatter (scan fused into scatter) -------
__global__ __launch_bounds__(256)
void pass_count(const float* __restrict__ logits, const float* __restrict__ b2,
                int* __restrict__ cnts)
{
  __shared__ int lcnt[NEXP];
  const int t = threadIdx.x;
  const int row = blockIdx.x * 256 + t;
  if (t < NEXP) lcnt[t] = 0;
  float l[8]; load_logits(logits, b2, row, l);
  int i0, i1; float l0, l1;
  top2(l, i0, l0, i1, l1);
  __syncthreads();
  atomicAdd(&lcnt[i0], 1);
  atomicAdd(&lcnt[i1], 1);
  __syncthreads();
  if (t < NEXP) atomicAdd(&cnts[t], lcnt[t]);
}

// scan of cnts (8 ints) is recomputed locally here and in moe_fused — cnts is
// final before either launches (stream order). Block 0 also publishes offs
// globally for the non-fused fallback path.
__global__ __launch_bounds__(256)
void pass_scatter(const float* __restrict__ logits, const float* __restrict__ b2,
                  const int* __restrict__ cnts, int* __restrict__ offsG,
                  int* __restrict__ cnts2,
                  int* __restrict__ rowsC, float* __restrict__ gateC)
{
  __shared__ int lcnt[NEXP];
  __shared__ int sbase[NEXP];
  __shared__ int sOffs[NEXP + 1];
  const int t = threadIdx.x;
  const int row = blockIdx.x * 256 + t;
  if (t < NEXP) lcnt[t] = 0;
  if (t == 0) {
    int s = 0;
#pragma unroll
    for (int e = 0; e < NEXP; ++e) { sOffs[e] = s; s += cnts[e]; }
    sOffs[NEXP] = s;
    if (blockIdx.x == 0) {
#pragma unroll
      for (int e = 0; e <= NEXP; ++e) offsG[e] = sOffs[e];
    }
  }
  float l[8]; load_logits(logits, b2, row, l);
  int i0, i1; float l0, l1;
  top2(l, i0, l0, i1, l1);
  float tt = expf(l1 - l0);            // <= 1
  float g0 = 1.f / (1.f + tt);
  float g1 = tt / (1.f + tt);
  __syncthreads();
  int r0 = atomicAdd(&lcnt[i0], 1);
  int r1 = atomicAdd(&lcnt[i1], 1);
  __syncthreads();
  if (t < NEXP) sbase[t] = atomicAdd(&cnts2[t], lcnt[t]);
  __syncthreads();
  int p0 = sOffs[i0] + sbase[i0] + r0;
  int p1 = sOffs[i1] + sbase[i1] + r1;
  rowsC[p0] = row; gateC[p0] = g0;
  rowsC[p1] = row; gateC[p1] = g1;
}

// ---- shared 8-phase machinery (verified R9-R16) ----
#define G8_BAR() do { __builtin_amdgcn_s_barrier(); \
                      __builtin_amdgcn_sched_barrier(0); } while (0)
#define G8_VM4() asm volatile("s_waitcnt vmcnt(4)" ::: "memory")
#define G8_VM0() asm volatile("s_waitcnt vmcnt(0)" ::: "memory")
#define G8_LGKM0() do { asm volatile("s_waitcnt lgkmcnt(0)" ::: "memory"); \
                        __builtin_amdgcn_sched_barrier(0); } while (0)
#define G8_LGKM8() asm volatile("s_waitcnt lgkmcnt(8)" ::: "memory")

#define READ_A(aL, mfh, Af) do { \
  _Pragma("unroll") for (int mf = 0; mf < 4; ++mf) { \
    Af[mf][0] = *(const bf16x8*)&(aL)[((mfh)*4+mf)*1024 + aBase + swzC[0]]; \
    Af[mf][1] = *(const bf16x8*)&(aL)[((mfh)*4+mf)*1024 + aBase + swzC[1]]; \
  } } while (0)

#define READ_B(bL, nfh, Bf) do { \
  _Pragma("unroll") for (int nf = 0; nf < 2; ++nf) { \
    Bf[nf][0] = *(const bf16x8*)&(bL)[((nfh)*2+nf)*1024 + bBase + swzC[0]]; \
    Bf[nf][1] = *(const bf16x8*)&(bL)[((nfh)*2+nf)*1024 + bBase + swzC[1]]; \
  } } while (0)

#define MFMA_Q(mfh, nfh, Af, Bf) do { \
  __builtin_amdgcn_s_setprio(1); \
  _Pragma("unroll") for (int kk = 0; kk < 2; ++kk) \
  _Pragma("unroll") for (int mf = 0; mf < 4; ++mf) \
  _Pragma("unroll") for (int nf = 0; nf < 2; ++nf) \
    acc[(mfh)*4+mf][(nfh)*2+nf] = __builtin_amdgcn_mfma_f32_16x16x32_bf16( \
        Af[mf][kk], Bf[nf][kk], acc[(mfh)*4+mf][(nfh)*2+nf], 0, 0, 0); \
  __builtin_amdgcn_s_setprio(0); } while (0)

#define G8_KLOOP() do { \
  stB(0, 0); stB(0, 1); stA(0, 0); stA(0, 1); \
  stB(1, 0); stB(1, 1); \
  G8_VM4(); \
  G8_BAR(); \
  bf16x8 Af[4][2], Bf0[2][2], Bf1[2][2]; \
  const int numI = numK >> 1; \
  for (int it = 0; it < numI; ++it) { \
    const int t1 = 2 * it + 1, t2 = 2 * it + 2, t3 = 2 * it + 3; \
    const bool last = (t2 >= numK); \
    READ_A(aH[0], 0, Af); \
    READ_B(bH[0], 0, Bf0); \
    stA(t1, 0); \
    G8_LGKM8(); \
    G8_BAR(); \
    G8_LGKM0(); \
    MFMA_Q(0, 0, Af, Bf0); \
    G8_BAR(); \
    READ_B(bH[0], 1, Bf1); \
    stA(t1, 1); \
    G8_BAR(); \
    G8_LGKM0(); \
    MFMA_Q(0, 1, Af, Bf1); \
    G8_BAR(); \
    READ_A(aH[0], 1, Af); \
    if (!last) stB(t2, 0); \
    G8_BAR(); \
    G8_LGKM0(); \
    MFMA_Q(1, 1, Af, Bf1); \
    G8_BAR(); \
    if (!last) stB(t2, 1); \
    G8_BAR(); \
    MFMA_Q(1, 0, Af, Bf0); \
    if (last) { G8_VM0(); } else { G8_VM4(); } \
    G8_BAR(); \
    READ_A(aH[1], 0, Af); \
    READ_B(bH[1], 0, Bf0); \
    if (!last) stA(t2, 0); \
    G8_LGKM8(); \
    G8_BAR(); \
    G8_LGKM0(); \
    MFMA_Q(0, 0, Af, Bf0); \
    G8_BAR(); \
    READ_B(bH[1], 1, Bf1); \
    if (!last) stA(t2, 1); \
    G8_BAR(); \
    G8_LGKM0(); \
    MFMA_Q(0, 1, Af, Bf1); \
    G8_BAR(); \
    READ_A(aH[1], 1, Af); \
    if (t3 < numK) stB(t3, 0); \
    G8_BAR(); \
    G8_LGKM0(); \
    MFMA_Q(1, 1, Af, Bf1); \
    G8_BAR(); \
    if (t3 < numK) stB(t3, 1); \
    G8_BAR(); \
    MFMA_Q(1, 0, Af, Bf0); \
    if (!last) { G8_VM4(); } \
    G8_BAR(); \
  } \
} while (0)

// ============================================================================
// gemm8p (R11-verified): 8-phase 256x256 dense GEMM — used for the ROUTER.
// ============================================================================
template<int EPI>
__global__ __launch_bounds__(512, 2)
void gemm8p(const u16* __restrict__ A0, const u16* __restrict__ B0,
            int lda, int ldb, int K, int NT, int Mdense,
            const float* __restrict__ bias,
            u16* __restrict__ Cbf, int ldc)
{
  const unsigned swz = xcd_swz(blockIdx.x, gridDim.x);
  const int mt = (int)(swz / (unsigned)NT);
  if (mt >= Mdense / 256) return;
  const int m0 = mt * 256, Mq = Mdense;
  const int n0 = (int)(swz % (unsigned)NT) * 256;
  const float* bi = bias;

  __shared__ alignas(16) u16 As[2][2][128 * 64];
  __shared__ alignas(16) u16 Bs[2][2][128 * 64];

  const int t = threadIdx.x;
  const int numK = K >> 6;

  const u16* aP[2][2]; const u16* bP[2][2]; int dst[2];
#pragma unroll
  for (int j = 0; j < 2; ++j) {
    const int gdx = j * 512 + t;
    const int rw = gdx >> 3;
    const int cs = ((gdx & 7) ^ (rw & 7)) << 3;
    dst[j] = gdx * 8;
#pragma unroll
    for (int h = 0; h < 2; ++h) {
      aP[h][j] = A0 + (size_t)(m0 + h * 128 + rw) * lda + cs;
      bP[h][j] = B0 + (size_t)(n0 + h * 128 + rw) * ldb + cs;
    }
  }
  auto stA = [&](int tile, int h) {
    async16(aP[h][0] + (size_t)tile * 64, &As[tile & 1][h][dst[0]]);
    async16(aP[h][1] + (size_t)tile * 64, &As[tile & 1][h][dst[1]]);
  };
  auto stB = [&](int tile, int h) {
    async16(bP[h][0] + (size_t)tile * 64, &Bs[tile & 1][h][dst[0]]);
    async16(bP[h][1] + (size_t)tile * 64, &Bs[tile & 1][h][dst[1]]);
  };

  const int lane = t & 63, wv = t >> 6;
  const int wr = wv >> 2, wc = wv & 3;
  const int fr = lane & 15, fq = lane >> 4;
  int swzC[2];
#pragma unroll
  for (int kk = 0; kk < 2; ++kk)
    swzC[kk] = ((kk * 4 + fq) ^ (fr & 7)) << 3;
  const int aBase = fr * 64;
  const int bBase = (wc & 1) * 4096 + fr * 64;
  const u16* aH[2] = { &As[0][wr][0], &As[1][wr][0] };
  const u16* bH[2] = { &Bs[0][wc >> 1][0], &Bs[1][wc >> 1][0] };

  f32x4 acc[8][4];
#pragma unroll
  for (int i = 0; i < 8; ++i)
#pragma unroll
    for (int j = 0; j < 4; ++j) acc[i][j] = (f32x4){0.f, 0.f, 0.f, 0.f};

  G8_KLOOP();

  float bv[4];
#pragma unroll
  for (int nf = 0; nf < 4; ++nf) bv[nf] = bi[n0 + wc * 64 + nf * 16 + fr];
#pragma unroll
  for (int mf = 0; mf < 8; ++mf)
#pragma unroll
    for (int r = 0; r < 4; ++r) {
      const int m = m0 + wr * 128 + mf * 16 + fq * 4 + r;
      if (m < Mq) {
#pragma unroll
        for (int nf = 0; nf < 4; ++nf) {
          const int n = n0 + wc * 64 + nf * 16 + fr;
          Cbf[(size_t)m * ldc + n] = f2bf(fmaxf(acc[mf][nf][r] + bv[nf], 0.f));
        }
      }
    }
}

// ============================================================================
// moe_fused (R14-verified core; R17: offs/tileOffs2 computed locally from
// cnts — cnts is final before launch, same values scan_kernel produced).
// class c = blockIdx.x & 7; qc[c]: G1 items [272c,272c+272); qc[8+c]: G2
// items [68c,68c+68) (same mt range -> deps in-class). Pop: own-A, own-B,
// steal. Readiness: agent-scope RELEASE add / ACQUIRE spin. vmcnt(0) drain
// before each item keeps the counted schedule exact.
// ============================================================================
__global__ __launch_bounds__(512, 1)
void moe_fused(const u16* __restrict__ xnhi, const u16* __restrict__ ew1t,
               const u16* __restrict__ ew2t,
               const int* __restrict__ counts,
               const int* __restrict__ rowsC, const float* __restrict__ gatesC,
               const float* __restrict__ e_b1, const float* __restrict__ e_b2,
               u16* __restrict__ Hbuf, float* __restrict__ out,
               int* __restrict__ qc, int* __restrict__ ready)
{
  constexpr int NT1 = HID / 256;            // 16
  constexpr int NT2 = DIM / 256;            // 4
  constexpr int W1 = NT1 * MAXMT2;          // 2176
  constexpr int CHA = W1 / 8;               // 272
  constexpr int CHB = (NT2 * MAXMT2) / 8;   // 68

  __shared__ alignas(16) u16 As[2][2][128 * 64];
  __shared__ alignas(16) u16 Bs[2][2][128 * 64];
  __shared__ int sh_w;
  __shared__ int sOffs[NEXP], sTO2[NEXP + 1];

  const int t = threadIdx.x;
  const int cls = (int)(blockIdx.x & 7);
  const int lane = t & 63, wv = t >> 6;
  const int wr = wv >> 2, wc = wv & 3;
  const int fr = lane & 15, fq = lane >> 4;
  int swzC[2];
#pragma unroll
  for (int kk = 0; kk < 2; ++kk)
    swzC[kk] = ((kk * 4 + fq) ^ (fr & 7)) << 3;
  const int aBase = fr * 64;
  const int bBase = (wc & 1) * 4096 + fr * 64;
  const u16* aH[2] = { &As[0][wr][0], &As[1][wr][0] };
  const u16* bH[2] = { &Bs[0][wc >> 1][0], &Bs[1][wc >> 1][0] };

  if (t == 0) {
    int s = 0, ts2 = 0;
#pragma unroll
    for (int e = 0; e < NEXP; ++e) {
      sOffs[e] = s; s += counts[e];
      sTO2[e] = ts2; ts2 += (counts[e] + 255) >> 8;
    }
    sTO2[NEXP] = ts2;
  }
  // visible after the first loop-top __syncthreads

  for (;;) {
    __syncthreads();                        // LDS + sh_w reuse fence
    if (t == 0) {
      int enc = -1;
      for (int k = 0; k < 8 && enc < 0; ++k) {
        const int v = (cls + k) & 7;
        int w = atomicAdd(&qc[v], 1);
        if (w < CHA) { enc = v * CHA + w; break; }
        w = atomicAdd(&qc[8 + v], 1);
        if (w < CHB) { enc = W1 + v * CHB + w; break; }
      }
      sh_w = enc;
    }
    __syncthreads();
    const int w = sh_w;
    if (w < 0) return;
    const bool isG1 = (w < W1);
    const int wl = isG1 ? w : (w - W1);
    const int NT = isG1 ? NT1 : NT2;
    const int mt = wl / NT;
    if (mt >= sTO2[NEXP]) continue;
    int e = 0;
#pragma unroll
    for (int i = 1; i < NEXP; ++i) if (sTO2[i] <= mt) e = i;
    const int m0 = (mt - sTO2[e]) * 256;
    const int Mq = counts[e];
    if (m0 >= Mq) continue;
    const int off = sOffs[e];
    const int n0 = (wl % NT) * 256;

    if (!isG1) {
      if (t == 0) {
        while (__hip_atomic_load(ready + mt, __ATOMIC_ACQUIRE,
                                 __HIP_MEMORY_SCOPE_AGENT) < NT1)
          __builtin_amdgcn_s_sleep(8);
      }
      __syncthreads();
    }

    const int lda = isG1 ? DIM : HID;       // = ldb
    const int numK = (isG1 ? DIM : HID) >> 6;
    const u16* Asrc = isG1 ? xnhi : Hbuf;
    const u16* B = isG1 ? (ew1t + (size_t)e * HID * DIM)
                        : (ew2t + (size_t)e * DIM * HID);
    const float* bi = isG1 ? (e_b1 + (size_t)e * HID)
                           : (e_b2 + (size_t)e * DIM);
    const int* rows = rowsC + off;

    const u16* aP[2][2]; const u16* bP[2][2]; int dst[2];
#pragma unroll
    for (int j = 0; j < 2; ++j) {
      const int gdx = j * 512 + t;
      const int rw = gdx >> 3;
      const int cs = ((gdx & 7) ^ (rw & 7)) << 3;
      dst[j] = gdx * 8;
#pragma unroll
      for (int h = 0; h < 2; ++h) {
        const int grow = m0 + h * 128 + rw;
        const int amc = grow < Mq ? grow : (Mq - 1);
        const size_t agr = isG1 ? (size_t)rows[amc] : (size_t)(off + amc);
        aP[h][j] = Asrc + agr * lda + cs;
        bP[h][j] = B + (size_t)(n0 + h * 128 + rw) * lda + cs;
      }
    }
    auto stA = [&](int tile, int h) {
      async16(aP[h][0] + (size_t)tile * 64, &As[tile & 1][h][dst[0]]);
      async16(aP[h][1] + (size_t)tile * 64, &As[tile & 1][h][dst[1]]);
    };
    auto stB = [&](int tile, int h) {
      async16(bP[h][0] + (size_t)tile * 64, &Bs[tile & 1][h][dst[0]]);
      async16(bP[h][1] + (size_t)tile * 64, &Bs[tile & 1][h][dst[1]]);
    };

    f32x4 acc[8][4];
#pragma unroll
    for (int i = 0; i < 8; ++i)
#pragma unroll
      for (int j = 0; j < 4; ++j) acc[i][j] = (f32x4){0.f, 0.f, 0.f, 0.f};

    // drain prior item's stores/atomics so counted vmcnt stays exact
    asm volatile("s_waitcnt vmcnt(0)" ::: "memory");

    G8_KLOOP();

    // ---- epilogue ----
    float bv[4];
#pragma unroll
    for (int nf = 0; nf < 4; ++nf) bv[nf] = bi[n0 + wc * 64 + nf * 16 + fr];

    if (isG1) {
#pragma unroll
      for (int mf = 0; mf < 8; ++mf)
#pragma unroll
        for (int r = 0; r < 4; ++r) {
          const int m = m0 + wr * 128 + mf * 16 + fq * 4 + r;
          if (m < Mq) {
#pragma unroll
            for (int nf = 0; nf < 4; ++nf) {
              const int n = n0 + wc * 64 + nf * 16 + fr;
              Hbuf[(size_t)(off + m) * HID + n] =
                  f2bf(fmaxf(acc[mf][nf][r] + bv[nf], 0.f));
            }
          }
        }
      __syncthreads();   // drains every thread's stores (waitcnt pre-barrier)
      if (t == 0)
        __hip_atomic_fetch_add(ready + mt, 1, __ATOMIC_RELEASE,
                               __HIP_MEMORY_SCOPE_AGENT);
    } else {
#pragma unroll
      for (int mf = 0; mf < 8; ++mf)
#pragma unroll
        for (int r = 0; r < 4; ++r) {
          const int m = m0 + wr * 128 + mf * 16 + fq * 4 + r;
          if (m < Mq) {
            const size_t orow = (size_t)rows[m];
            const float g = gatesC[off + m];
#pragma unroll
            for (int nf = 0; nf < 4; ++nf) {
              const int n = n0 + wc * 64 + nf * 16 + fr;
              atomicAdd(&out[orow * DIM + n], g * (acc[mf][nf][r] + bv[nf]));
            }
          }
        }
    }
  }
}

// ---------------- GEMM: legacy 128x128 kernel (fix-GEMM, fallback) ----------
template<bool SPLIT, int EPI, bool GATHER>
__global__ __launch_bounds__(256, 2)
void gemm_bt(const u16* __restrict__ A0, const u16* __restrict__ A1,
             const u16* __restrict__ B0, const u16* __restrict__ B1,
             int lda, int ldb, int K, int M,
             const int* __restrict__ counts, int expertArg,
             const int* __restrict__ offs,
             const int* __restrict__ rowsC, const float* __restrict__ gatesC,
             const float* __restrict__ bias,
             const float* __restrict__ w2, float* __restrict__ logits,
             u16* __restrict__ Cbf, float* __restrict__ Cf32, int ldc)
{
  int expert, m0, n0;
  if (counts == nullptr) {
    const unsigned nwg = gridDim.x * gridDim.y;
    const unsigned flat = blockIdx.y * gridDim.x + blockIdx.x;
    const unsigned swz = xcd_swz(flat, nwg);
    expert = expertArg;
    m0 = (int)(swz / gridDim.x) * 128;
    n0 = (int)(swz % gridDim.x) * 128;
  } else {
    expert = expertArg;
    m0 = blockIdx.y * 128;
    n0 = blockIdx.x * 128;
  }

  const int Mq = counts ? counts[expert] : M;
  if (m0 >= Mq) return;
  const int off = offs ? offs[expert] : 0;
  const int* rows = rowsC ? rowsC + off : nullptr;
  const float* gates = gatesC ? gatesC + off : nullptr;
  const u16* B = B0;
  const u16* Bl = SPLIT ? B1 : nullptr;
  const float* bi = bias;
  const int z = (int)blockIdx.z;
  const int zOff = z * K;

  __shared__ u16 As0[128 * 32], Bs0[128 * 32];
  __shared__ u16 As1[SPLIT ? 128 * 32 : 8], Bs1[SPLIT ? 128 * 32 : 8];

  const int t = threadIdx.x;
  size_t aoff[2]; int acodd[2]; size_t boff[2];
#pragma unroll
  for (int i = 0; i < 2; ++i) {
    int gdx = i * 256 + t;
    int ar = gdx >> 2, ac = (gdx & 3) * 8;
    int am = m0 + ar;
    int amc = am < Mq ? am : (Mq - 1);
    int agr = GATHER ? rows[amc] : amc;
    aoff[i] = (size_t)agr * lda + ac + zOff;
    boff[i] = (size_t)(n0 + ar) * ldb + ac + zOff;
    acodd[i] = gdx * 8;
  }

  f32x4 acc[4][4];
#pragma unroll
  for (int i = 0; i < 4; ++i)
#pragma unroll
    for (int j = 0; j < 4; ++j) acc[i][j] = (f32x4){0.f, 0.f, 0.f, 0.f};

  const int lane = t & 63, wv = t >> 6;
  const int wm = (wv >> 1) * 64, wn = (wv & 1) * 64;
  const int fr = lane & 15, fq = lane >> 4;

  for (int k0 = 0; k0 < K; k0 += 32) {
    __syncthreads();
#pragma unroll
    for (int i = 0; i < 2; ++i) {
      async16(A0 + aoff[i] + k0, &As0[acodd[i]]);
      async16(B + boff[i] + k0, &Bs0[acodd[i]]);
      if (SPLIT) {
        async16(A1 + aoff[i] + k0, &As1[acodd[i]]);
        async16(Bl + boff[i] + k0, &Bs1[acodd[i]]);
      }
    }
    __syncthreads();
    bf16x8 af[4], bfr[4], af1[4], bf1[4];
#pragma unroll
    for (int xi = 0; xi < 4; ++xi) {
      af[xi]  = *(const bf16x8*)&As0[(wm + xi * 16 + fr) * 32 + fq * 8];
      bfr[xi] = *(const bf16x8*)&Bs0[(wn + xi * 16 + fr) * 32 + fq * 8];
      if (SPLIT) {
        af1[xi] = *(const bf16x8*)&As1[(wm + xi * 16 + fr) * 32 + fq * 8];
        bf1[xi] = *(const bf16x8*)&Bs1[(wn + xi * 16 + fr) * 32 + fq * 8];
      }
    }
#pragma unroll
    for (int mt = 0; mt < 4; ++mt)
#pragma unroll
      for (int nt = 0; nt < 4; ++nt) {
        acc[mt][nt] = __builtin_amdgcn_mfma_f32_16x16x32_bf16(af[mt], bfr[nt], acc[mt][nt], 0, 0, 0);
        if (SPLIT) {
          acc[mt][nt] = __builtin_amdgcn_mfma_f32_16x16x32_bf16(af[mt], bf1[nt], acc[mt][nt], 0, 0, 0);
          acc[mt][nt] = __builtin_amdgcn_mfma_f32_16x16x32_bf16(af1[mt], bfr[nt], acc[mt][nt], 0, 0, 0);
        }
      }
  }

  if constexpr (EPI == 3) {
    float w2v[4][8]; float b1v[4];
#pragma unroll
    for (int nt = 0; nt < 4; ++nt) {
      const int n = n0 + wn + nt * 16 + fr;
      b1v[nt] = bi[n];
      const float4* wp = (const float4*)(w2 + (size_t)n * 8);
      float4 wa = wp[0], wb = wp[1];
      w2v[nt][0] = wa.x; w2v[nt][1] = wa.y; w2v[nt][2] = wa.z; w2v[nt][3] = wa.w;
      w2v[nt][4] = wb.x; w2v[nt][5] = wb.y; w2v[nt][6] = wb.z; w2v[nt][7] = wb.w;
    }
#pragma unroll
    for (int mt = 0; mt < 4; ++mt) {
      float pe[4][8];
#pragma unroll
      for (int r = 0; r < 4; ++r)
#pragma unroll
        for (int ee = 0; ee < 8; ++ee) pe[r][ee] = 0.f;
#pragma unroll
      for (int nt = 0; nt < 4; ++nt)
#pragma unroll
        for (int r = 0; r < 4; ++r) {
          float v = fmaxf(acc[mt][nt][r] + b1v[nt], 0.f);
#pragma unroll
          for (int ee = 0; ee < 8; ++ee) pe[r][ee] += v * w2v[nt][ee];
        }
#pragma unroll
      for (int offx = 1; offx < 16; offx <<= 1)
#pragma unroll
        for (int r = 0; r < 4; ++r)
#pragma unroll
          for (int ee = 0; ee < 8; ++ee)
            pe[r][ee] += __shfl_xor(pe[r][ee], offx, 64);
      if (fr == 0) {
#pragma unroll
        for (int r = 0; r < 4; ++r) {
          const int m = m0 + wm + mt * 16 + fq * 4 + r;
          if (m < Mq) {
            const int lrow = GATHER ? rows[m] : m;
#pragma unroll
            for (int ee = 0; ee < 8; ++ee)
              atomicAdd(&logits[(size_t)lrow * 8 + ee], pe[r][ee]);
          }
        }
      }
    }
    return;
  }

#pragma unroll
  for (int mt = 0; mt < 4; ++mt) {
#pragma unroll
    for (int nt = 0; nt < 4; ++nt) {
      const int n = n0 + wn + nt * 16 + fr;
      const float bvv = (z == 0) ? bi[n] : 0.f;
#pragma unroll
      for (int r = 0; r < 4; ++r) {
        const int m = m0 + wm + mt * 16 + fq * 4 + r;
        if (m < Mq) {
          float v = acc[mt][nt][r] + bvv;
          if constexpr (EPI == 1) {
            Cbf[(size_t)m * ldc + n] = f2bf(fmaxf(v, 0.f));
          } else {
            atomicAdd(&Cf32[(size_t)rows[m] * ldc + n], gates[m] * v);
          }
        }
      }
    }
  }
}

extern "C" void kernel_launch(void* const* d_in, const int* in_sizes, int n_in,
                              void* d_out, int out_size, void* d_ws, size_t ws_size,
                              hipStream_t stream)
{
  const float* x    = (const float*)d_in[0];
  const float* ln_g = (const float*)d_in[1];
  const float* ln_b = (const float*)d_in[2];
  const float* r_w1 = (const float*)d_in[3];
  const float* r_b1 = (const float*)d_in[4];
  const float* r_w2 = (const float*)d_in[5];
  const float* r_b2 = (const float*)d_in[6];
  const float* e_w1 = (const float*)d_in[7];
  const float* e_b1 = (const float*)d_in[8];
  const float* e_w2 = (const float*)d_in[9];
  const float* e_b2 = (const float*)d_in[10];
  float* out = (float*)d_out;

  char* ws = (char*)d_ws;
  const size_t MB = 1024ull * 1024ull;
  u16*   xnhi = (u16*)(ws);                 // 32 MB  [N, D] bf16
  u16*   xnlo = (u16*)(ws + 32 * MB);       // 32 MB
  u16*   rw1h = (u16*)(ws + 64 * MB);       // 4 MB   [HR, D] bf16
  u16*   rw1l = (u16*)(ws + 68 * MB);       // 4 MB
  u16*   ew1t = (u16*)(ws + 72 * MB);       // 64 MB  [E][H, D] bf16
  u16*   ew2t = (u16*)(ws + 136 * MB);      // 64 MB  [E][D, H] bf16
  float* logits = (float*)(ws + 200 * MB);                    // 512 KB [N, 8]
  int*   rowsC  = (int*)(ws + 200 * MB + 512 * 1024);         // 128 KB [2N]
  float* gateC  = (float*)(ws + 200 * MB + 640 * 1024);       // 128 KB [2N]
  int*   fixL   = (int*)(ws + 200 * MB + 768 * 1024);         // 64 KB  [N]
  int*   cntb   = (int*)(ws + 200 * MB + 832 * 1024);         // 256 B
  int*   cnts   = cntb;          // [8]
  int*   cnts2  = cntb + 8;      // [8]
  int*   offs   = cntb + 16;     // [9] (fallback only; written by scatter blk0)
  int*   cntFix = cntb + 25;     // [1]
  int*   qready = (int*)(ws + 200 * MB + 836 * 1024);  // 4 KB: qc[16] + ready
  int*   qc     = qready;
  int*   ready  = qready + 16;
  u16*   Hbuf = (u16*)(ws + 201 * MB);      // fused: 256 MB [2N, H]; HrB aliases
  u16*   HrB  = Hbuf;                       // 64 MB [N, HR] bf16 (router hidden)
  (void)in_sizes; (void)n_in; (void)out_size;

  const bool fused = ws_size >= 458ull * MB;

  // one memset covers cntb (+832K, 256B) and qready (+836K, 4KB)
  hipMemsetAsync(cntb, 0, 8192, stream);

  // all 3 weight transposes in one launch
  transpose_all<<<dim3(16896), 256, 0, stream>>>(
      r_w1, rw1h, rw1l, e_w1, ew1t, e_w2, ew2t);

  ln_kernel<<<N_TOK, 256, 0, stream>>>(x, ln_g, ln_b, xnhi, xnlo, out);

  // router: HrB = bf16(relu(xn @ r_w1 + b1)) — 8-phase DENSE
  gemm8p<1><<<dim3((HR / 256) * (N_TOK / 256)), 512, 0, stream>>>(
      xnhi, rw1h, DIM, DIM, DIM, HR / 256, N_TOK, r_b1, HrB, HR);

  logits_kernel<<<N_TOK, 256, 0, stream>>>(HrB, r_w2, logits);

  pass_flag<<<N_TOK / 256, 256, 0, stream>>>(logits, r_b2, fixL, cntFix);

  gemm_bt<true, 3, true><<<dim3(HR / 128, N_TOK / 128), 256, 0, stream>>>(
      xnhi, xnlo, rw1h, rw1l, DIM, DIM, DIM, N_TOK,
      cntFix, 0, nullptr, fixL, nullptr, r_b1, r_w2, logits,
      nullptr, nullptr, 0);

  pass_count<<<N_TOK / 256, 256, 0, stream>>>(logits, r_b2, cnts);
  // scan fused into scatter (local prefix over 8 ints; blk0 publishes offs)
  pass_scatter<<<N_TOK / 256, 256, 0, stream>>>(logits, r_b2, cnts, offs,
                                                cnts2, rowsC, gateC);

  if (fused) {
    // persistent dual-GEMM: per-XCD queues, fine-grained G1->G2 readiness
    moe_fused<<<dim3(256), 512, 0, stream>>>(
        xnhi, ew1t, ew2t, cnts, rowsC, gateC,
        e_b1, e_b2, Hbuf, out, qc, ready);
  } else {
    for (int e = 0; e < NEXP; ++e) {
      gemm_bt<false, 1, true><<<dim3(HID / 128, N_TOK / 128), 256, 0, stream>>>(
          xnhi, nullptr, ew1t + (size_t)e * HID * DIM, nullptr,
          DIM, DIM, DIM, N_TOK,
          cnts, e, offs, rowsC, nullptr, e_b1 + (size_t)e * HID, nullptr, nullptr,
          Hbuf, nullptr, HID);
      gemm_bt<false, 2, false><<<dim3(DIM / 128, N_TOK / 128, 2), 256, 0, stream>>>(
          Hbuf, nullptr, ew2t + (size_t)e * DIM * HID, nullptr,
          HID, HID, HID / 2, N_TOK,
          cnts, e, offs, rowsC, gateC, e_b2 + (size_t)e * DIM, nullptr, nullptr,
          nullptr, out, DIM);
    }
  }
}